// Round 3
// baseline (2251.316 us; speedup 1.0000x reference)
//
#include <hip/hip_runtime.h>
#include <hip/hip_bf16.h>

typedef __bf16 bf16_t;
typedef __bf16 bf16x8 __attribute__((ext_vector_type(8)));
typedef __bf16 bf16x4 __attribute__((ext_vector_type(4)));
typedef float  f32x4  __attribute__((ext_vector_type(4)));

#define BN_   16384
#define DIN_  128
#define DEM_  64
#define DH_   400
#define DHP_  416   // K padded to 32-multiple
#define DHA_  512   // N padded to 128-tile coverage
#define GH_   256
#define MM_   4
#define EPS_  1e-5f

// ---------------- dtype detector: low-16 of f32 words decodes to garbage bf16
__global__ __launch_bounds__(256) void k_detect(const unsigned* __restrict__ w,
                                                int* __restrict__ flag)
{
  __shared__ int cnt[256];
  int c = 0;
  for (int i = 0; i < 16; ++i) {
    unsigned v = w[threadIdx.x * 16 + i];
    float lo = __uint_as_float((v & 0xffffu) << 16);
    if (!(fabsf(lo) < 1e4f)) ++c;   // NaN/inf/huge -> garbage
  }
  cnt[threadIdx.x] = c;
  __syncthreads();
  if (threadIdx.x == 0) {
    int t = 0;
    for (int i = 0; i < 256; ++i) t += cnt[i];
    flag[0] = (t > 64) ? 1 : 0;     // 1 = inputs are float32
  }
}

// ---------------- MFMA C/D layout probe: writes 0 (row=(l>>4)*4+e,col=l&15) or 1 (transposed)
__global__ void k_mfmaprobe(int* __restrict__ layC)
{
  int l = threadIdx.x & 63;
  bf16x8 av, bv;
#pragma unroll
  for (int e = 0; e < 8; ++e) { av[e] = (bf16_t)0.f; bv[e] = (bf16_t)0.f; }
  if ((l >> 4) == 0) av[0] = (bf16_t)(float)(l & 15);  // A[r][0] = r
  if (l == 0)        bv[0] = (bf16_t)1.f;              // B[0][0] = 1
  f32x4 acc = {0.f, 0.f, 0.f, 0.f};
  acc = __builtin_amdgcn_mfma_f32_16x16x32_bf16(av, bv, acc, 0, 0, 0);
  // D[r][c] = r*(c==0).  L0: lane1 holds D[4q+e][1]=0.  L1: lane1 reg0 holds D[1][0]=1.
  if (l == 1) layC[0] = (acc[0] > 0.5f) ? 1 : 0;
}

// ---------------- dtype-agnostic converters ---------------------------------
__global__ __launch_bounds__(256) void k_convert(
    const void* __restrict__ src, bf16_t* __restrict__ dst, int n,
    const int* __restrict__ flag)
{
  const int f = flag[0];
  for (int i = blockIdx.x * 256 + threadIdx.x; i < n; i += gridDim.x * 256)
    dst[i] = f ? (bf16_t)((const float*)src)[i] : ((const bf16_t*)src)[i];
}

struct SmallTab {
  const void* src[26];
  bf16_t*     dst[26];
  int         n[26];
};

__global__ __launch_bounds__(256) void k_convert_smalls(SmallTab tab, const int* __restrict__ flag)
{
  const int f = flag[0];
  const void* s = tab.src[blockIdx.x];
  bf16_t*     d = tab.dst[blockIdx.x];
  const int   n = tab.n[blockIdx.x];
  for (int i = threadIdx.x; i < n; i += 256)
    d[i] = f ? (bf16_t)((const float*)s)[i] : ((const bf16_t*)s)[i];
}

// ---------------- weight transpose (padded, zero-filled, dtype-agnostic) ----
__global__ __launch_bounds__(256) void k_transpose(
    const void* __restrict__ W, bf16_t* __restrict__ Wt,
    int K, int N, int KP, int NPa, const int* __restrict__ flag)
{
  const int f = flag[0];
  int idx = blockIdx.x * 256 + threadIdx.x;
  if (idx >= NPa * KP) return;
  int n = idx / KP, k = idx - n * KP;
  float v = 0.f;
  if (k < K && n < N)
    v = f ? ((const float*)W)[(size_t)k * N + n]
          : (float)((const bf16_t*)W)[(size_t)k * N + n];
  Wt[idx] = (bf16_t)v;
}

// ---------------------------------------------------------------- GEMM core
__device__ __forceinline__ void gemm_core(
    const bf16_t* __restrict__ A, int lda,
    const bf16_t* __restrict__ Bt, int ldb,
    int ksteps, int row0, int col0, int rr, int qq,
    f32x4 (&acc)[4][4])
{
  const bf16_t* a0 = A + (size_t)(row0 + rr) * lda + qq * 8;
  const bf16_t* b0 = Bt + (size_t)(col0 + rr) * ldb + qq * 8;
  for (int ks = 0; ks < ksteps; ++ks) {
    bf16x8 av[4], bv[4];
#pragma unroll
    for (int i = 0; i < 4; ++i)
      av[i] = *reinterpret_cast<const bf16x8*>(a0 + (size_t)i * 16 * lda);
#pragma unroll
    for (int i = 0; i < 4; ++i)
      bv[i] = *reinterpret_cast<const bf16x8*>(b0 + (size_t)i * 16 * ldb);
#pragma unroll
    for (int i = 0; i < 4; ++i)
#pragma unroll
      for (int j = 0; j < 4; ++j)
        acc[i][j] = __builtin_amdgcn_mfma_f32_16x16x32_bf16(av[i], bv[j], acc[i][j], 0, 0, 0);
    a0 += 32; b0 += 32;
  }
}

__device__ __forceinline__ void acc_zero(f32x4 (&acc)[4][4]) {
  const f32x4 z = {0.f, 0.f, 0.f, 0.f};
#pragma unroll
  for (int i = 0; i < 4; ++i)
#pragma unroll
    for (int j = 0; j < 4; ++j) acc[i][j] = z;
}

// ------------------------------------------------- generic bias(+relu) GEMM
template<bool RELU, bool OUTF32>
__global__ __launch_bounds__(256) void k_gemm_bias(
    const bf16_t* __restrict__ A, int lda, int ksteps,
    const bf16_t* __restrict__ Bt, int ldb,
    const bf16_t* __restrict__ bias, int nbias,
    void* __restrict__ outv, int ldo, int nout,
    const int* __restrict__ layC)
{
  const int lay = layC[0];
  const int w = threadIdx.x >> 6, lane = threadIdx.x & 63;
  const int rr = lane & 15, qq = lane >> 4;
  const int row0 = blockIdx.x * 128 + (w >> 1) * 64;
  const int col0 = blockIdx.y * 128 + (w & 1) * 64;
  f32x4 acc[4][4]; acc_zero(acc);
  gemm_core(A, lda, Bt, ldb, ksteps, row0, col0, rr, qq, acc);
#pragma unroll
  for (int j = 0; j < 4; ++j) {
#pragma unroll
    for (int i = 0; i < 4; ++i) {
#pragma unroll
      for (int e = 0; e < 4; ++e) {
        int ri = lay ? rr : qq * 4 + e;
        int ci = lay ? qq * 4 + e : rr;
        int row = row0 + i * 16 + ri;
        int col = col0 + j * 16 + ci;
        if (col >= nout) continue;
        float bv = (col < nbias) ? (float)bias[col] : 0.f;
        float v = acc[i][j][e] + bv;
        if (RELU) v = fmaxf(v, 0.f);
        if (OUTF32) ((float*)outv)[(size_t)row * ldo + col] = v;
        else ((bf16_t*)outv)[(size_t)row * ldo + col] = (bf16_t)v;
      }
    }
  }
}

// ---- base layer 2: out_pre=A@W2+b2; outA=relu(out_pre); emb1=relu(emb0*out_pre)
__global__ __launch_bounds__(256) void k_gemm_base2(
    const bf16_t* __restrict__ A, const bf16_t* __restrict__ Bt,
    const bf16_t* __restrict__ bias, const bf16_t* __restrict__ emb0,
    bf16_t* __restrict__ outA, bf16_t* __restrict__ emb1,
    const int* __restrict__ layC)
{
  const int lay = layC[0];
  const int w = threadIdx.x >> 6, lane = threadIdx.x & 63;
  const int rr = lane & 15, qq = lane >> 4;
  const int row0 = blockIdx.x * 128 + (w >> 1) * 64;
  const int col0 = blockIdx.y * 128 + (w & 1) * 64;
  f32x4 acc[4][4]; acc_zero(acc);
  gemm_core(A, DHP_, Bt, DHP_, 13, row0, col0, rr, qq, acc);
#pragma unroll
  for (int j = 0; j < 4; ++j) {
#pragma unroll
    for (int i = 0; i < 4; ++i) {
#pragma unroll
      for (int e = 0; e < 4; ++e) {
        int ri = lay ? rr : qq * 4 + e;
        int ci = lay ? qq * 4 + e : rr;
        int row = row0 + i * 16 + ri;
        int col = col0 + j * 16 + ci;
        if (col >= DHP_) continue;
        float bv = (col < DH_) ? (float)bias[col] : 0.f;
        float op = acc[i][j][e] + bv;
        float o  = fmaxf(op, 0.f);
        float e0 = (float)emb0[(size_t)row * DHP_ + col];
        float m1 = fmaxf(e0 * op, 0.f);
        outA[(size_t)row * DHP_ + col] = (bf16_t)o;
        emb1[(size_t)row * DHP_ + col] = (bf16_t)m1;
      }
    }
  }
}

// ---- module GEMM: mo[b][m][:] = A_m[b][:] @ W'_m + b'_m
__global__ __launch_bounds__(256) void k_gemm_mod(
    const bf16_t* __restrict__ Abase, int lda, int mstride,
    const bf16_t* __restrict__ WtM, const float* __restrict__ bM,
    bf16_t* __restrict__ mo, const int* __restrict__ layC)
{
  const int lay = layC[0];
  const int m = blockIdx.z;
  const int w = threadIdx.x >> 6, lane = threadIdx.x & 63;
  const int rr = lane & 15, qq = lane >> 4;
  const int row0 = blockIdx.x * 128 + (w >> 1) * 64;
  const int col0 = blockIdx.y * 128 + (w & 1) * 64;
  f32x4 acc[4][4]; acc_zero(acc);
  gemm_core(Abase + (size_t)m * mstride, lda, WtM + (size_t)m * DHA_ * DHP_, DHP_,
            13, row0, col0, rr, qq, acc);
#pragma unroll
  for (int j = 0; j < 4; ++j) {
#pragma unroll
    for (int i = 0; i < 4; ++i) {
#pragma unroll
      for (int e = 0; e < 4; ++e) {
        int ri = lay ? rr : qq * 4 + e;
        int ci = lay ? qq * 4 + e : rr;
        int row = row0 + i * 16 + ri;
        int col = col0 + j * 16 + ci;
        if (col >= DHP_) continue;
        float v = acc[i][j][e] + bM[m * DHA_ + col];
        mo[((size_t)row * MM_ + m) * DHP_ + col] = (bf16_t)v;
      }
    }
  }
}

// ---------------- deterministic per-(m,col) sum/sumsq partials over batch ----
__global__ __launch_bounds__(256) void k_stats(
    const bf16_t* __restrict__ src, int nm,
    float* __restrict__ ps, float* __restrict__ pq)
{
  __shared__ float ls[256], lq[256];
  const int m = blockIdx.x, cg = blockIdx.y, rc = blockIdx.z;
  const int t = threadIdx.x;
  const int c = cg * 64 + (t & 63);
  const int r0 = rc * 2048 + (t >> 6);
  float s = 0.f, q = 0.f;
  if (c < DHP_) {
    for (int i = 0; i < 512; ++i) {
      int r = r0 + i * 4;
      float v = (float)src[((size_t)r * nm + m) * DHP_ + c];
      s += v; q += v * v;
    }
  }
  ls[t] = s; lq[t] = q;
  __syncthreads();
  if (t < 64) {
    float S = ls[t] + ls[t + 64] + ls[t + 128] + ls[t + 192];
    float Q = lq[t] + lq[t + 64] + lq[t + 128] + lq[t + 192];
    int idx = ((rc * MM_ + m) * 7 + cg) * 64 + t;
    ps[idx] = S; pq[idx] = Q;
  }
}

// ---------------- partials -> BN scale/shift per (m,d) -----------------------
__global__ __launch_bounds__(256) void k_bnprep(
    const float* __restrict__ ps, const float* __restrict__ pq, int per_m,
    const bf16_t* __restrict__ g, const bf16_t* __restrict__ b,
    float* __restrict__ s_o, float* __restrict__ t_o)
{
  int idx = blockIdx.x * 256 + threadIdx.x;
  if (idx >= MM_ * DHP_) return;
  int m = idx / DHP_, k = idx - m * DHP_;
  float s = 0.f, t = 0.f;
  if (k < DH_) {
    int mm = per_m ? m : 0;
    int cg = k >> 6, cl = k & 63;
    float S = 0.f, Q = 0.f;
#pragma unroll
    for (int rc = 0; rc < 8; ++rc) {
      S += ps[((rc * MM_ + mm) * 7 + cg) * 64 + cl];
      Q += pq[((rc * MM_ + mm) * 7 + cg) * 64 + cl];
    }
    float mean = S * (1.f / BN_);
    float var  = fmaxf(Q * (1.f / BN_) - mean * mean, 0.f);
    float rstd = rsqrtf(var + EPS_);
    s = (float)g[m * DH_ + k] * rstd;
    t = (float)b[m * DH_ + k] - mean * s;
  }
  s_o[m * DHP_ + k] = s;
  t_o[m * DHP_ + k] = t;
}

// ------------------------------- fold BN1 scale into module weights (transposed)
__global__ __launch_bounds__(256) void k_foldA(
    const bf16_t* __restrict__ modW, const float* __restrict__ s1v,
    bf16_t* __restrict__ WtM)
{
  int idx = blockIdx.x * 256 + threadIdx.x;  // 4*512*416
  int m = idx / (DHA_ * DHP_);
  int r = idx - m * (DHA_ * DHP_);
  int n = r / DHP_;
  int k = r - n * DHP_;
  bf16_t v = (bf16_t)0.f;
  if (k < DH_ && n < DH_)
    v = (bf16_t)(s1v[m * DHP_ + k] * (float)modW[((size_t)m * DH_ + k) * DH_ + n]);
  WtM[idx] = v;
}

// b'_m[n] = mod_b[m][n] + sum_k shift[m][k]*W[m][k][n]
__global__ __launch_bounds__(256) void k_foldB(
    const bf16_t* __restrict__ modW, const bf16_t* __restrict__ modb,
    const float* __restrict__ t1v, float* __restrict__ bM)
{
  __shared__ float ls[256];
  const int m = blockIdx.x, ncg = blockIdx.y;
  const int t = threadIdx.x;
  const int n = ncg * 64 + (t & 63);
  const int ks = t >> 6;   // 0..3, 100 k each
  float a = 0.f;
  if (n < DH_) {
    for (int k = ks * 100; k < ks * 100 + 100; ++k)
      a += t1v[m * DHP_ + k] * (float)modW[((size_t)m * DH_ + k) * DH_ + n];
  }
  ls[t] = a;
  __syncthreads();
  if (t < 64) {
    int nn = ncg * 64 + t;
    float v = ls[t] + ls[t + 64] + ls[t + 128] + ls[t + 192];
    if (nn < DH_) v += (float)modb[m * DH_ + nn];
    else v = 0.f;
    bM[m * DHA_ + nn] = v;
  }
}

// ---------------- routing mix: mi[b][j][:] = relu(sum_k bn2(mo)[b,k,:]*w[b,j,k])
__global__ __launch_bounds__(256) void k_mix(
    const bf16_t* __restrict__ mo, const float* __restrict__ s2v, const float* __restrict__ t2v,
    const float* __restrict__ wbuf, int woff, bf16_t* __restrict__ mi)
{
  const int total = BN_ * MM_ * 52;
  for (int ch = blockIdx.x * 256 + threadIdx.x; ch < total; ch += gridDim.x * 256) {
    int c  = ch % 52;
    int jm = (ch / 52) & 3;
    int b  = ch / 208;
    const float* wp = wbuf + (size_t)b * 52 + woff + jm * 4;
    float w4[4] = {wp[0], wp[1], wp[2], wp[3]};
    float a[8] = {0.f, 0.f, 0.f, 0.f, 0.f, 0.f, 0.f, 0.f};
#pragma unroll
    for (int k = 0; k < 4; ++k) {
      bf16x8 v = *reinterpret_cast<const bf16x8*>(mo + ((size_t)b * MM_ + k) * DHP_ + c * 8);
#pragma unroll
      for (int e = 0; e < 8; ++e) {
        float x = (float)v[e] * s2v[k * DHP_ + c * 8 + e] + t2v[k * DHP_ + c * 8 + e];
        a[e] = fmaf(x, w4[k], a[e]);
      }
    }
    bf16x8 ov;
#pragma unroll
    for (int e = 0; e < 8; ++e) ov[e] = (bf16_t)fmaxf(a[e], 0.f);
    *reinterpret_cast<bf16x8*>(mi + ((size_t)b * MM_ + jm) * DHP_ + c * 8) = ov;
  }
}

// --------------------------- gating cascade: 1 sample/wave, ~5KB LDS ---------
__global__ __launch_bounds__(256) void k_gate(
    const float* __restrict__ emb,
    const bf16_t* __restrict__ gw0_w, const bf16_t* __restrict__ gw0_b,
    const bf16_t* __restrict__ c1_w,  const bf16_t* __restrict__ c1_b,
    const bf16_t* __restrict__ gw1_w, const bf16_t* __restrict__ gw1_b,
    const bf16_t* __restrict__ c2_w,  const bf16_t* __restrict__ c2_b,
    const bf16_t* __restrict__ gw2_w, const bf16_t* __restrict__ gw2_b,
    const bf16_t* __restrict__ cL_w,  const bf16_t* __restrict__ cL_b,
    const bf16_t* __restrict__ gwL_w, const bf16_t* __restrict__ gwL_b,
    float* __restrict__ wbuf)
{
  __shared__ float VBUF[4][256];
  __shared__ float FLAT[4][64];
  const int wave = threadIdx.x >> 6, lane = threadIdx.x & 63;
  const int b = blockIdx.x * 4 + wave;
  float* vb = VBUF[wave];
  float* fl = FLAT[wave];

  float e4[4];
  {
    f32x4 ev = *reinterpret_cast<const f32x4*>(emb + (size_t)b * GH_ + lane * 4);
#pragma unroll
    for (int e = 0; e < 4; ++e) {
      e4[e] = ev[e];
      vb[lane * 4 + e] = fmaxf(e4[e], 0.f);   // relu(emb) feeds gw0
    }
  }
  __syncthreads();

  const int jj = lane & 15;

  auto gw_phase = [&](const bf16_t* W, const bf16_t* Bb, int foff) {
    const int hh = lane >> 4;     // 0..3, 64 k each
    float a = 0.f;
    for (int kk = 0; kk < 64; ++kk) {
      int k = hh * 64 + kk;
      a = fmaf(vb[k], (float)W[k * 16 + jj], a);
    }
    a += __shfl_xor(a, 16);
    a += __shfl_xor(a, 32);
    a += (float)Bb[jj];
    float m1 = fmaxf(a, __shfl_xor(a, 1));
    float mx = fmaxf(m1, __shfl_xor(m1, 2));
    float ex = __expf(a - mx);
    float sx = ex + __shfl_xor(ex, 1);
    float sm = sx + __shfl_xor(sx, 2);
    float wv = ex / sm;
    if (lane < 16) { fl[foff + jj] = wv; wbuf[(size_t)b * 52 + foff + jj] = wv; }
    __syncthreads();
  };

  auto cond_phase = [&](const bf16_t* W, const bf16_t* Bb, int tcount) {
    float a4[4];
    bf16x4 bb = *reinterpret_cast<const bf16x4*>(Bb + lane * 4);
#pragma unroll
    for (int e = 0; e < 4; ++e) a4[e] = (float)bb[e];
    for (int t = 0; t < tcount; ++t) {
      float f = fl[t];
      bf16x4 wv = *reinterpret_cast<const bf16x4*>(W + t * 256 + lane * 4);
#pragma unroll
      for (int e = 0; e < 4; ++e) a4[e] = fmaf(f, (float)wv[e], a4[e]);
    }
#pragma unroll
    for (int e = 0; e < 4; ++e) vb[lane * 4 + e] = fmaxf(a4[e] * e4[e], 0.f);
    __syncthreads();
  };

  gw_phase(gw0_w, gw0_b, 0);
  cond_phase(c1_w, c1_b, 16);
  gw_phase(gw1_w, gw1_b, 16);
  cond_phase(c2_w, c2_b, 32);
  gw_phase(gw2_w, gw2_b, 32);
  cond_phase(cL_w, cL_b, 48);
  {
    const int j4 = lane & 3, h16 = lane >> 2;  // 16 groups x 16 k
    float a = 0.f;
    for (int kk = 0; kk < 16; ++kk) {
      int k = h16 * 16 + kk;
      a = fmaf(vb[k], (float)gwL_w[k * 4 + j4], a);
    }
    a += __shfl_xor(a, 4);
    a += __shfl_xor(a, 8);
    a += __shfl_xor(a, 16);
    a += __shfl_xor(a, 32);
    a += (float)gwL_b[j4];
    float m1 = fmaxf(a, __shfl_xor(a, 1));
    float mx = fmaxf(m1, __shfl_xor(m1, 2));
    float ex = __expf(a - mx);
    float sx = ex + __shfl_xor(ex, 1);
    float sm = sx + __shfl_xor(sx, 2);
    if (lane < 4) wbuf[(size_t)b * 52 + 48 + j4] = ex / sm;
  }
}

// ------------- final: BN2-affine, last_weight mix, relu, @last_w + last_b ----
// canaries (all NaN-proof): 2000=w0 softmax bad, 1000=last softmax bad,
// 600=non-finite mo/s2 seen, 400=non-finite result
__global__ __launch_bounds__(256) void k_final(
    const bf16_t* __restrict__ mo, const float* __restrict__ s2v, const float* __restrict__ t2v,
    const float* __restrict__ wbuf, const bf16_t* __restrict__ last_w,
    const bf16_t* __restrict__ last_b, void* __restrict__ outv,
    const int* __restrict__ flag)
{
  const int f32out = flag[0];
  const int wave = threadIdx.x >> 6, lane = threadIdx.x & 63;
  const int b = blockIdx.x * 4 + wave;
  const float* lwp = wbuf + (size_t)b * 52 + 48;
  float lm[4] = {lwp[0], lwp[1], lwp[2], lwp[3]};
  const float* w0p = wbuf + (size_t)b * 52;
  float sw0 = w0p[0] + w0p[1] + w0p[2] + w0p[3];
  float slm = lm[0] + lm[1] + lm[2] + lm[3];
  bool bad = false;
  float p[8] = {0.f, 0.f, 0.f, 0.f, 0.f, 0.f, 0.f, 0.f};
  for (int t = 0; t < 7; ++t) {
    int d = t * 64 + lane;
    if (d < DH_) {
      float acc = 0.f;
#pragma unroll
      for (int m = 0; m < 4; ++m) {
        float xm = (float)mo[((size_t)b * MM_ + m) * DHP_ + d];
        float sv = s2v[m * DHP_ + d];
        if (!(fabsf(xm) < 1e8f) || !(fabsf(sv) < 1e8f)) bad = true;
        float x = xm * sv + t2v[m * DHP_ + d];
        acc = fmaf(x, lm[m], acc);
      }
      float v = fmaxf(acc, 0.f);
      bf16x8 wv = *reinterpret_cast<const bf16x8*>(last_w + (size_t)d * 8);
#pragma unroll
      for (int j = 0; j < 8; ++j) p[j] = fmaf(v, (float)wv[j], p[j]);
    }
  }
#pragma unroll
  for (int j = 0; j < 8; ++j) {
    p[j] += __shfl_xor(p[j], 1);
    p[j] += __shfl_xor(p[j], 2);
    p[j] += __shfl_xor(p[j], 4);
    p[j] += __shfl_xor(p[j], 8);
    p[j] += __shfl_xor(p[j], 16);
    p[j] += __shfl_xor(p[j], 32);
  }
  unsigned long long bb = __ballot(bad);
  float sel = p[0];
#pragma unroll
  for (int j = 1; j < 8; ++j) if (lane == j) sel = p[j];
  if (lane < 8) {
    float res = sel + (float)last_b[lane];
    if (!(fabsf(res) < 1e4f)) res = 400.f;
    if (bb != 0ull) res = 600.f;
    if (!(slm > 0.97f && slm < 1.03f)) res = 1000.f;
    if (!(sw0 > 0.97f && sw0 < 1.03f)) res = 2000.f;
    if (f32out) ((float*)outv)[(size_t)b * 8 + lane] = res;
    else ((bf16_t*)outv)[(size_t)b * 8 + lane] = (bf16_t)res;
  }
}

// ======================================================================
extern "C" void kernel_launch(void* const* d_in, const int* in_sizes, int n_in,
                              void* d_out, int out_size, void* d_ws, size_t ws_size,
                              hipStream_t stream)
{
  (void)in_sizes; (void)n_in;
  const void* x_raw     = d_in[0];
  const void* emb_raw   = d_in[1];
  const void* base_w1   = d_in[2];
  const void* base_b1   = d_in[3];
  const void* base_w2   = d_in[4];
  const void* base_b2   = d_in[5];
  const void* em_w      = d_in[6];
  const void* em_b      = d_in[7];
  const void* gfc_w1    = d_in[8];
  const void* gfc_b1    = d_in[9];
  const void* gfc_w2    = d_in[10];
  const void* gfc_b2    = d_in[11];

  char* base = (char*)d_ws;
  size_t off = 0;
  auto alloc = [&](size_t bytes) -> char* {
    off = (off + 255) & ~(size_t)255;
    char* r = base + off; off += bytes; return r;
  };
  int*    dflag = (int*)   alloc(16);
  int*    layC  = (int*)   alloc(16);
  bf16_t* Wt1  = (bf16_t*)alloc((size_t)512 * 128 * 2);
  bf16_t* Wem  = (bf16_t*)alloc((size_t)512 * 64 * 2);
  bf16_t* Wt2  = (bf16_t*)alloc((size_t)512 * DHP_ * 2);
  bf16_t* Wg1  = (bf16_t*)alloc((size_t)256 * DHP_ * 2);
  bf16_t* Wg2  = (bf16_t*)alloc((size_t)256 * 256 * 2);
  bf16_t* WtM  = (bf16_t*)alloc((size_t)MM_ * DHA_ * DHP_ * 2);
  float*  bM   = (float*) alloc((size_t)MM_ * DHA_ * 4);
  bf16_t* xc   = (bf16_t*)alloc((size_t)BN_ * DIN_ * 2);
  bf16_t* embc = (bf16_t*)alloc((size_t)BN_ * DEM_ * 2);
  bf16_t* modWc= (bf16_t*)alloc((size_t)4 * MM_ * DH_ * DH_ * 2);
  bf16_t* out1 = (bf16_t*)alloc((size_t)BN_ * DHP_ * 2);
  bf16_t* emb0 = (bf16_t*)alloc((size_t)BN_ * DHP_ * 2);   // also reused for emb2
  bf16_t* outA = (bf16_t*)alloc((size_t)BN_ * DHP_ * 2);
  bf16_t* emb1 = (bf16_t*)alloc((size_t)BN_ * DHP_ * 2);
  float*  embF = (float*) alloc((size_t)BN_ * GH_ * 4);
  float*  wbuf = (float*) alloc((size_t)BN_ * 52 * 4);
  bf16_t* mo   = (bf16_t*)alloc((size_t)BN_ * MM_ * DHP_ * 2);
  bf16_t* mi   = (bf16_t*)alloc((size_t)BN_ * MM_ * DHP_ * 2);
  float* psA = (float*)alloc((size_t)8 * MM_ * 7 * 64 * 4);
  float* pqA = (float*)alloc((size_t)8 * MM_ * 7 * 64 * 4);
  float* psB = (float*)alloc((size_t)8 * MM_ * 7 * 64 * 4);
  float* pqB = (float*)alloc((size_t)8 * MM_ * 7 * 64 * 4);
  float* s1 = (float*)alloc((size_t)MM_ * DHP_ * 4);
  float* t1 = (float*)alloc((size_t)MM_ * DHP_ * 4);
  float* s2 = (float*)alloc((size_t)MM_ * DHP_ * 4);
  float* t2 = (float*)alloc((size_t)MM_ * DHP_ * 4);
  // converted small tensors
  const int NS = 26;
  const int sn[NS] = {400, 400, 400, 256, 256,
                      4096, 16, 4096, 256, 4096, 16, 8192, 256, 4096, 16,
                      12288, 256, 1024, 4,
                      6400, 6400, 6400, 6400, 6400, 3200, 8};
  const int si[NS] = {3, 5, 7, 9, 11,
                      12, 13, 14, 15, 16, 17, 18, 19, 20, 21,
                      22, 23, 24, 25,
                      26, 27, 29, 30, 31, 32, 33};
  bf16_t* sc[NS];
  for (int i = 0; i < NS; ++i) sc[i] = (bf16_t*)alloc((size_t)sn[i] * 2);
  bf16_t *b1c = sc[0], *b2c = sc[1], *embbc = sc[2], *g1bc = sc[3], *g2bc = sc[4];
  bf16_t *gw0w = sc[5], *gw0b = sc[6], *c1w = sc[7], *c1b = sc[8], *gw1w = sc[9],
         *gw1b = sc[10], *c2w = sc[11], *c2b = sc[12], *gw2w = sc[13], *gw2b = sc[14],
         *cLw = sc[15], *cLb = sc[16], *gwLw = sc[17], *gwLb = sc[18];
  bf16_t *bn1g = sc[19], *bn1b = sc[20], *modbc = sc[21], *bn2g = sc[22], *bn2b = sc[23];
  bf16_t *lastw = sc[24], *lastb = sc[25];

  if (off > ws_size) {  // workspace too small: fail visibly (zeros)
    hipMemsetAsync(d_out, 0, (size_t)out_size * 2, stream);
    return;
  }

  dim3 blk(256);
  // detection + probes
  k_detect<<<1, blk, 0, stream>>>((const unsigned*)x_raw, dflag);
  k_mfmaprobe<<<1, dim3(64), 0, stream>>>(layC);

  // conversions
  k_convert<<<dim3(2048), blk, 0, stream>>>(x_raw,   xc,    BN_ * DIN_, dflag);
  k_convert<<<dim3(1024), blk, 0, stream>>>(emb_raw, embc,  BN_ * DEM_, dflag);
  k_convert<<<dim3(2048), blk, 0, stream>>>(d_in[28], modWc, 4 * MM_ * DH_ * DH_, dflag);
  SmallTab tab;
  for (int i = 0; i < NS; ++i) { tab.src[i] = d_in[si[i]]; tab.dst[i] = sc[i]; tab.n[i] = sn[i]; }
  k_convert_smalls<<<dim3(NS), blk, 0, stream>>>(tab, dflag);

  // weight transposes (padded, zero-filled)
  k_transpose<<<dim3((512 * 128) / 256), blk, 0, stream>>>(base_w1, Wt1, DIN_, DH_, 128, 512, dflag);
  k_transpose<<<dim3((512 * 64) / 256),  blk, 0, stream>>>(em_w,    Wem, DEM_, DH_, 64, 512, dflag);
  k_transpose<<<dim3((512 * DHP_) / 256), blk, 0, stream>>>(base_w2, Wt2, DH_, DH_, DHP_, 512, dflag);
  k_transpose<<<dim3((256 * DHP_) / 256), blk, 0, stream>>>(gfc_w1, Wg1, DH_, GH_, DHP_, 256, dflag);
  k_transpose<<<dim3((256 * 256) / 256),  blk, 0, stream>>>(gfc_w2, Wg2, GH_, GH_, GH_, 256, dflag);

  // front MLPs
  k_gemm_bias<true , false><<<dim3(128, 4), blk, 0, stream>>>(xc, DIN_, 4, Wt1, 128, b1c, DH_, out1, DHP_, DHP_, layC);
  k_gemm_bias<false, false><<<dim3(128, 4), blk, 0, stream>>>(embc, DEM_, 2, Wem, 64, embbc, DH_, emb0, DHP_, DHP_, layC);
  k_gemm_base2<<<dim3(128, 4), blk, 0, stream>>>(out1, Wt2, b2c, emb0, outA, emb1, layC);
  bf16_t* emb2 = emb0;  // emb0 dead after base2 -> reuse
  k_gemm_bias<true , false><<<dim3(128, 2), blk, 0, stream>>>(emb1, DHP_, 13, Wg1, DHP_, g1bc, GH_, emb2, GH_, GH_, layC);
  k_gemm_bias<false, true ><<<dim3(128, 2), blk, 0, stream>>>(emb2, GH_, 8, Wg2, GH_, g2bc, GH_, embF, GH_, GH_, layC);

  // gating cascade
  k_gate<<<dim3(BN_ / 4), blk, 0, stream>>>(embF,
      gw0w, gw0b, c1w, c1b, gw1w, gw1b, c2w, c2b, gw2w, gw2b,
      cLw, cLb, gwLw, gwLb, wbuf);

  // layer 0
  k_stats<<<dim3(1, 7, 8), blk, 0, stream>>>(outA, 1, psA, pqA);
  k_bnprep<<<dim3(7), blk, 0, stream>>>(psA, pqA, 0, bn1g, bn1b, s1, t1);
  k_foldA<<<dim3((MM_ * DHA_ * DHP_) / 256), blk, 0, stream>>>(modWc, s1, WtM);
  k_foldB<<<dim3(4, 7), blk, 0, stream>>>(modWc, modbc, t1, bM);
  k_gemm_mod<<<dim3(128, 4, 4), blk, 0, stream>>>(outA, DHP_, 0, WtM, bM, mo, layC);
  k_stats<<<dim3(4, 7, 8), blk, 0, stream>>>(mo, MM_, psB, pqB);

  // layers 1..3
  for (int L = 1; L < 4; ++L) {
    k_bnprep<<<dim3(7), blk, 0, stream>>>(psB, pqB, 1,
        bn2g + (size_t)(L - 1) * MM_ * DH_, bn2b + (size_t)(L - 1) * MM_ * DH_, s2, t2);
    k_mix<<<dim3(832), blk, 0, stream>>>(mo, s2, t2, wbuf, (L - 1) * 16, mi);
    k_stats<<<dim3(4, 7, 8), blk, 0, stream>>>(mi, MM_, psA, pqA);
    k_bnprep<<<dim3(7), blk, 0, stream>>>(psA, pqA, 1,
        bn1g + (size_t)L * MM_ * DH_, bn1b + (size_t)L * MM_ * DH_, s1, t1);
    k_foldA<<<dim3((MM_ * DHA_ * DHP_) / 256), blk, 0, stream>>>(modWc + (size_t)L * MM_ * DH_ * DH_, s1, WtM);
    k_foldB<<<dim3(4, 7), blk, 0, stream>>>(modWc + (size_t)L * MM_ * DH_ * DH_, modbc + (size_t)L * MM_ * DH_, t1, bM);
    k_gemm_mod<<<dim3(128, 4, 4), blk, 0, stream>>>(mi, MM_ * DHP_, DHP_, WtM, bM, mo, layC);
    k_stats<<<dim3(4, 7, 8), blk, 0, stream>>>(mo, MM_, psB, pqB);
  }

  // final
  k_bnprep<<<dim3(7), blk, 0, stream>>>(psB, pqB, 1,
      bn2g + (size_t)3 * MM_ * DH_, bn2b + (size_t)3 * MM_ * DH_, s2, t2);
  k_final<<<dim3(BN_ / 4), blk, 0, stream>>>(mo, s2, t2, wbuf, lastw, lastb, d_out, dflag);
}

// Round 4
// 1044.926 us; speedup vs baseline: 2.1545x; 2.1545x over previous
//
#include <hip/hip_runtime.h>
#include <hip/hip_bf16.h>

typedef __bf16 bf16_t;
typedef __bf16 bf16x8 __attribute__((ext_vector_type(8)));
typedef __bf16 bf16x4 __attribute__((ext_vector_type(4)));
typedef float  f32x4  __attribute__((ext_vector_type(4)));

#define BN_   16384
#define DIN_  128
#define DEM_  64
#define DH_   400
#define DHP_  416   // K padded to 32-multiple
#define DHA_  512   // N padded to 128-tile coverage
#define GH_   256
#define MM_   4
#define EPS_  1e-5f

// ---------------- dtype detector: low-16 of f32 words decodes to garbage bf16
__global__ __launch_bounds__(256) void k_detect(const unsigned* __restrict__ w,
                                                int* __restrict__ flag)
{
  __shared__ int cnt[256];
  int c = 0;
  for (int i = 0; i < 16; ++i) {
    unsigned v = w[threadIdx.x * 16 + i];
    float lo = __uint_as_float((v & 0xffffu) << 16);
    if (!(fabsf(lo) < 1e4f)) ++c;
  }
  cnt[threadIdx.x] = c;
  __syncthreads();
  if (threadIdx.x == 0) {
    int t = 0;
    for (int i = 0; i < 256; ++i) t += cnt[i];
    flag[0] = (t > 64) ? 1 : 0;     // 1 = inputs are float32
  }
}

// ---------------- MFMA C/D layout probe
__global__ void k_mfmaprobe(int* __restrict__ layC)
{
  int l = threadIdx.x & 63;
  bf16x8 av, bv;
#pragma unroll
  for (int e = 0; e < 8; ++e) { av[e] = (bf16_t)0.f; bv[e] = (bf16_t)0.f; }
  if ((l >> 4) == 0) av[0] = (bf16_t)(float)(l & 15);
  if (l == 0)        bv[0] = (bf16_t)1.f;
  f32x4 acc = {0.f, 0.f, 0.f, 0.f};
  acc = __builtin_amdgcn_mfma_f32_16x16x32_bf16(av, bv, acc, 0, 0, 0);
  if (l == 1) layC[0] = (acc[0] > 0.5f) ? 1 : 0;
}

// ---------------- dtype-agnostic converters ---------------------------------
__global__ __launch_bounds__(256) void k_convert(
    const void* __restrict__ src, bf16_t* __restrict__ dst, int n,
    const int* __restrict__ flag)
{
  const int f = flag[0];
  for (int i = blockIdx.x * 256 + threadIdx.x; i < n; i += gridDim.x * 256)
    dst[i] = f ? (bf16_t)((const float*)src)[i] : ((const bf16_t*)src)[i];
}

struct SmallTab {
  const void* src[26];
  bf16_t*     dst[26];
  int         n[26];
};

__global__ __launch_bounds__(256) void k_convert_smalls(SmallTab tab, const int* __restrict__ flag)
{
  const int f = flag[0];
  const void* s = tab.src[blockIdx.x];
  bf16_t*     d = tab.dst[blockIdx.x];
  const int   n = tab.n[blockIdx.x];
  for (int i = threadIdx.x; i < n; i += 256)
    d[i] = f ? (bf16_t)((const float*)s)[i] : ((const bf16_t*)s)[i];
}

// ---------------- tiled transpose (+optional per-k scale fold), coalesced ----
// dst[z][n][k] = scale[z*DHP_+k] * src[z][k][n], zero-padded to [NPa][KP]
template<bool SCALED>
__global__ __launch_bounds__(256) void k_transT(
    const void* __restrict__ src, size_t srcStride,
    bf16_t* __restrict__ dst, size_t dstStride,
    int K, int N, int KP, int NPa,
    const float* __restrict__ scale, const int* __restrict__ flag)
{
  __shared__ float T[64][65];
  const int f = flag ? flag[0] : 0;
  const int z = blockIdx.z;
  const float*  sf = (const float*) src + (size_t)z * srcStride;
  const bf16_t* sb = (const bf16_t*)src + (size_t)z * srcStride;
  bf16_t* dp = dst + (size_t)z * dstStride;
  const int k0 = blockIdx.x * 64, n0 = blockIdx.y * 64;
  const int lr = threadIdx.x >> 6, ln = threadIdx.x & 63;
#pragma unroll
  for (int p = 0; p < 16; ++p) {
    int kl = p * 4 + lr;
    int k = k0 + kl, n = n0 + ln;
    float v = 0.f;
    if (k < K && n < N)
      v = f ? sf[(size_t)k * N + n] : (float)sb[(size_t)k * N + n];
    if (SCALED && k < K) v *= scale[z * DHP_ + k];
    T[kl][ln] = v;
  }
  __syncthreads();
#pragma unroll
  for (int p = 0; p < 16; ++p) {
    int nl = p * 4 + lr;
    int n = n0 + nl, k = k0 + ln;
    if (n < NPa && k < KP) dp[(size_t)n * KP + k] = (bf16_t)T[ln][nl];
  }
}

// ---------------------------------------------------------------- GEMM core
// A-frag: lane gives A[row0+(l&15)][k0+8*(l>>4)+e]; D: reg e -> row (l>>4)*4+e, col l&15 (lay=0)
template<int KS>
__device__ __forceinline__ void gemm_core(
    const bf16_t* __restrict__ A, int lda,
    const bf16_t* __restrict__ Bt, int ldb,
    int row0, int col0, int rr, int qq,
    f32x4 (&acc)[4][4])
{
  const bf16_t* a0 = A + (size_t)(row0 + rr) * lda + qq * 8;
  const bf16_t* b0 = Bt + (size_t)(col0 + rr) * ldb + qq * 8;
#pragma unroll 2
  for (int ks = 0; ks < KS; ++ks) {
    bf16x8 av[4], bv[4];
#pragma unroll
    for (int i = 0; i < 4; ++i)
      av[i] = *reinterpret_cast<const bf16x8*>(a0 + (size_t)i * 16 * lda);
#pragma unroll
    for (int i = 0; i < 4; ++i)
      bv[i] = *reinterpret_cast<const bf16x8*>(b0 + (size_t)i * 16 * ldb);
#pragma unroll
    for (int i = 0; i < 4; ++i)
#pragma unroll
      for (int j = 0; j < 4; ++j)
        acc[i][j] = __builtin_amdgcn_mfma_f32_16x16x32_bf16(av[i], bv[j], acc[i][j], 0, 0, 0);
    a0 += 32; b0 += 32;
  }
}

__device__ __forceinline__ void acc_zero(f32x4 (&acc)[4][4]) {
  const f32x4 z = {0.f, 0.f, 0.f, 0.f};
#pragma unroll
  for (int i = 0; i < 4; ++i)
#pragma unroll
    for (int j = 0; j < 4; ++j) acc[i][j] = z;
}

// ------------------------------------------------- generic bias(+relu) GEMM
template<int KS, bool RELU, bool OUTF32>
__global__ __launch_bounds__(256) void k_gemm_bias(
    const bf16_t* __restrict__ A, int lda,
    const bf16_t* __restrict__ Bt, int ldb,
    const bf16_t* __restrict__ bias, int nbias,
    void* __restrict__ outv, int ldo, int nout,
    const int* __restrict__ layC)
{
  const int lay = layC[0];
  const int w = threadIdx.x >> 6, lane = threadIdx.x & 63;
  const int rr = lane & 15, qq = lane >> 4;
  const int row0 = blockIdx.x * 128 + (w >> 1) * 64;
  const int col0 = blockIdx.y * 128 + (w & 1) * 64;
  if (col0 >= nout) return;
  f32x4 acc[4][4]; acc_zero(acc);
  gemm_core<KS>(A, lda, Bt, ldb, row0, col0, rr, qq, acc);
#pragma unroll
  for (int j = 0; j < 4; ++j) {
#pragma unroll
    for (int i = 0; i < 4; ++i) {
#pragma unroll
      for (int e = 0; e < 4; ++e) {
        int ri = lay ? rr : qq * 4 + e;
        int ci = lay ? qq * 4 + e : rr;
        int row = row0 + i * 16 + ri;
        int col = col0 + j * 16 + ci;
        if (col >= nout) continue;
        float bv = (col < nbias) ? (float)bias[col] : 0.f;
        float v = acc[i][j][e] + bv;
        if (RELU) v = fmaxf(v, 0.f);
        if (OUTF32) ((float*)outv)[(size_t)row * ldo + col] = v;
        else ((bf16_t*)outv)[(size_t)row * ldo + col] = (bf16_t)v;
      }
    }
  }
}

// ---- base layer 2: out_pre=A@W2+b2; outA=relu(out_pre); emb1=relu(emb0*out_pre)
__global__ __launch_bounds__(256) void k_gemm_base2(
    const bf16_t* __restrict__ A, const bf16_t* __restrict__ Bt,
    const bf16_t* __restrict__ bias, const bf16_t* __restrict__ emb0,
    bf16_t* __restrict__ outA, bf16_t* __restrict__ emb1,
    const int* __restrict__ layC)
{
  const int lay = layC[0];
  const int w = threadIdx.x >> 6, lane = threadIdx.x & 63;
  const int rr = lane & 15, qq = lane >> 4;
  const int row0 = blockIdx.x * 128 + (w >> 1) * 64;
  const int col0 = blockIdx.y * 128 + (w & 1) * 64;
  if (col0 >= DHP_) return;
  f32x4 acc[4][4]; acc_zero(acc);
  gemm_core<13>(A, DHP_, Bt, DHP_, row0, col0, rr, qq, acc);
#pragma unroll
  for (int j = 0; j < 4; ++j) {
#pragma unroll
    for (int i = 0; i < 4; ++i) {
#pragma unroll
      for (int e = 0; e < 4; ++e) {
        int ri = lay ? rr : qq * 4 + e;
        int ci = lay ? qq * 4 + e : rr;
        int row = row0 + i * 16 + ri;
        int col = col0 + j * 16 + ci;
        if (col >= DHP_) continue;
        float bv = (col < DH_) ? (float)bias[col] : 0.f;
        float op = acc[i][j][e] + bv;
        float o  = fmaxf(op, 0.f);
        float e0 = (float)emb0[(size_t)row * DHP_ + col];
        float m1 = fmaxf(e0 * op, 0.f);
        outA[(size_t)row * DHP_ + col] = (bf16_t)o;
        emb1[(size_t)row * DHP_ + col] = (bf16_t)m1;
      }
    }
  }
}

// ---- module GEMM: mo[b][m][:] = A_m[b][:] @ W'_m + b'_m
__global__ __launch_bounds__(256) void k_gemm_mod(
    const bf16_t* __restrict__ Abase, int lda, int mstride,
    const bf16_t* __restrict__ WtM, const float* __restrict__ bM,
    bf16_t* __restrict__ mo, const int* __restrict__ layC)
{
  const int lay = layC[0];
  const int m = blockIdx.z;
  const int w = threadIdx.x >> 6, lane = threadIdx.x & 63;
  const int rr = lane & 15, qq = lane >> 4;
  const int row0 = blockIdx.x * 128 + (w >> 1) * 64;
  const int col0 = blockIdx.y * 128 + (w & 1) * 64;
  if (col0 >= DHP_) return;
  f32x4 acc[4][4]; acc_zero(acc);
  gemm_core<13>(Abase + (size_t)m * mstride, lda, WtM + (size_t)m * DHA_ * DHP_, DHP_,
                row0, col0, rr, qq, acc);
#pragma unroll
  for (int j = 0; j < 4; ++j) {
#pragma unroll
    for (int i = 0; i < 4; ++i) {
#pragma unroll
      for (int e = 0; e < 4; ++e) {
        int ri = lay ? rr : qq * 4 + e;
        int ci = lay ? qq * 4 + e : rr;
        int row = row0 + i * 16 + ri;
        int col = col0 + j * 16 + ci;
        if (col >= DHP_) continue;
        float v = acc[i][j][e] + bM[m * DHA_ + col];
        mo[((size_t)row * MM_ + m) * DHP_ + col] = (bf16_t)v;
      }
    }
  }
}

// ---------------- coalesced per-(m,col) sum/sumsq partials over batch --------
// grid (nm, 64); block 256 = 4 subrows x 64 lanes; each subrow-thread does 64 rows
__global__ __launch_bounds__(256) void k_stats(
    const bf16_t* __restrict__ src, int nm,
    float* __restrict__ ps, float* __restrict__ pq)
{
  __shared__ float lsum[4 * 52 * 8], lsq[4 * 52 * 8];
  const int m = blockIdx.x, bc = blockIdx.y;
  const int sub = threadIdx.x >> 6, lane = threadIdx.x & 63;
  float s[8], q[8];
#pragma unroll
  for (int e = 0; e < 8; ++e) { s[e] = 0.f; q[e] = 0.f; }
  if (lane < 52) {
    for (int i = 0; i < 64; ++i) {
      int b = bc * 256 + sub + i * 4;
      bf16x8 v = *reinterpret_cast<const bf16x8*>(src + ((size_t)b * nm + m) * DHP_ + lane * 8);
#pragma unroll
      for (int e = 0; e < 8; ++e) {
        float f = (float)v[e];
        s[e] += f; q[e] += f * f;
      }
    }
#pragma unroll
    for (int e = 0; e < 8; ++e) {
      lsum[(sub * 52 + lane) * 8 + e] = s[e];
      lsq [(sub * 52 + lane) * 8 + e] = q[e];
    }
  }
  __syncthreads();
  for (int idx = threadIdx.x; idx < 416; idx += 256) {
    float S = lsum[idx] + lsum[416 + idx] + lsum[832 + idx] + lsum[1248 + idx];
    float Q = lsq [idx] + lsq [416 + idx] + lsq [832 + idx] + lsq [1248 + idx];
    ps[((size_t)bc * MM_ + m) * DHP_ + idx] = S;
    pq[((size_t)bc * MM_ + m) * DHP_ + idx] = Q;
  }
}

// ---------------- partials -> BN scale/shift per (m,d) -----------------------
__global__ __launch_bounds__(256) void k_bnprep(
    const float* __restrict__ ps, const float* __restrict__ pq, int per_m,
    const bf16_t* __restrict__ g, const bf16_t* __restrict__ b,
    float* __restrict__ s_o, float* __restrict__ t_o)
{
  int idx = blockIdx.x * 256 + threadIdx.x;
  if (idx >= MM_ * DHP_) return;
  int m = idx / DHP_, k = idx - m * DHP_;
  float s = 0.f, t = 0.f;
  if (k < DH_) {
    int mm = per_m ? m : 0;
    float S = 0.f, Q = 0.f;
    for (int bc = 0; bc < 64; ++bc) {
      S += ps[((size_t)bc * MM_ + mm) * DHP_ + k];
      Q += pq[((size_t)bc * MM_ + mm) * DHP_ + k];
    }
    float mean = S * (1.f / BN_);
    float var  = fmaxf(Q * (1.f / BN_) - mean * mean, 0.f);
    float rstd = rsqrtf(var + EPS_);
    s = (float)g[m * DH_ + k] * rstd;
    t = (float)b[m * DH_ + k] - mean * s;
  }
  s_o[m * DHP_ + k] = s;
  t_o[m * DHP_ + k] = t;
}

// b'_m[n] = mod_b[m][n] + sum_k shift[m][k]*W[m][k][n]  (coalesced on n)
__global__ __launch_bounds__(256) void k_foldB(
    const bf16_t* __restrict__ modW, const bf16_t* __restrict__ modb,
    const float* __restrict__ t1v, float* __restrict__ bM)
{
  __shared__ float ls[256];
  const int m = blockIdx.x, ncg = blockIdx.y;
  const int t = threadIdx.x;
  const int n = ncg * 64 + (t & 63);
  const int ks = t >> 6;
  float a = 0.f;
  if (n < DH_) {
    for (int k = ks * 100; k < ks * 100 + 100; ++k)
      a += t1v[m * DHP_ + k] * (float)modW[((size_t)m * DH_ + k) * DH_ + n];
  }
  ls[t] = a;
  __syncthreads();
  if (t < 64) {
    int nn = ncg * 64 + t;
    float v = ls[t] + ls[t + 64] + ls[t + 128] + ls[t + 192];
    if (nn < DH_) v += (float)modb[m * DH_ + nn];
    else v = 0.f;
    bM[m * DHA_ + nn] = v;
  }
  // zero the tail cols 448..511 once (ncg==6 covers 384..447)
  if (ncg == 6 && t < 64) bM[m * DHA_ + 448 + t] = 0.f;
}

// ---------------- routing mix: mi[b][j][:] = relu(sum_k bn2(mo)[b,k,:]*w[b,j,k])
// wave-per-sample; affine coeffs hoisted to registers (lane-invariant across b)
__global__ __launch_bounds__(256) void k_mix(
    const bf16_t* __restrict__ mo, const float* __restrict__ s2v, const float* __restrict__ t2v,
    const float* __restrict__ wbuf, int woff, bf16_t* __restrict__ mi)
{
  const int wave = threadIdx.x >> 6, lane = threadIdx.x & 63;
  const int d0 = lane * 8;
  float sx[4][8], tx[4][8];
  if (lane < 52) {
#pragma unroll
    for (int k = 0; k < 4; ++k)
#pragma unroll
      for (int e = 0; e < 8; ++e) {
        sx[k][e] = s2v[k * DHP_ + d0 + e];
        tx[k][e] = t2v[k * DHP_ + d0 + e];
      }
  }
  for (int b = blockIdx.x * 4 + wave; b < BN_; b += gridDim.x * 4) {
    float wv = (lane < 16) ? wbuf[(size_t)b * 52 + woff + lane] : 0.f;
    if (lane < 52) {
      float x[4][8];
#pragma unroll
      for (int k = 0; k < 4; ++k) {
        bf16x8 v = *reinterpret_cast<const bf16x8*>(mo + ((size_t)b * MM_ + k) * DHP_ + d0);
#pragma unroll
        for (int e = 0; e < 8; ++e)
          x[k][e] = (float)v[e] * sx[k][e] + tx[k][e];
      }
#pragma unroll
      for (int j = 0; j < 4; ++j) {
        float w0 = __shfl(wv, j * 4 + 0), w1 = __shfl(wv, j * 4 + 1);
        float w2 = __shfl(wv, j * 4 + 2), w3 = __shfl(wv, j * 4 + 3);
        bf16x8 ov;
#pragma unroll
        for (int e = 0; e < 8; ++e) {
          float a = x[0][e] * w0 + x[1][e] * w1 + x[2][e] * w2 + x[3][e] * w3;
          ov[e] = (bf16_t)fmaxf(a, 0.f);
        }
        *reinterpret_cast<bf16x8*>(mi + ((size_t)b * MM_ + j) * DHP_ + d0) = ov;
      }
    }
  }
}

// --------------------------- gating cascade: 1 sample/wave, ~5KB LDS ---------
__global__ __launch_bounds__(256) void k_gate(
    const float* __restrict__ emb,
    const bf16_t* __restrict__ gw0_w, const bf16_t* __restrict__ gw0_b,
    const bf16_t* __restrict__ c1_w,  const bf16_t* __restrict__ c1_b,
    const bf16_t* __restrict__ gw1_w, const bf16_t* __restrict__ gw1_b,
    const bf16_t* __restrict__ c2_w,  const bf16_t* __restrict__ c2_b,
    const bf16_t* __restrict__ gw2_w, const bf16_t* __restrict__ gw2_b,
    const bf16_t* __restrict__ cL_w,  const bf16_t* __restrict__ cL_b,
    const bf16_t* __restrict__ gwL_w, const bf16_t* __restrict__ gwL_b,
    float* __restrict__ wbuf)
{
  __shared__ float VBUF[4][256];
  __shared__ float FLAT[4][64];
  const int wave = threadIdx.x >> 6, lane = threadIdx.x & 63;
  const int b = blockIdx.x * 4 + wave;
  float* vb = VBUF[wave];
  float* fl = FLAT[wave];

  float e4[4];
  {
    f32x4 ev = *reinterpret_cast<const f32x4*>(emb + (size_t)b * GH_ + lane * 4);
#pragma unroll
    for (int e = 0; e < 4; ++e) {
      e4[e] = ev[e];
      vb[lane * 4 + e] = fmaxf(e4[e], 0.f);
    }
  }
  __syncthreads();

  const int jj = lane & 15;

  auto gw_phase = [&](const bf16_t* W, const bf16_t* Bb, int foff) {
    const int hh = lane >> 4;
    float a = 0.f;
    for (int kk = 0; kk < 64; ++kk) {
      int k = hh * 64 + kk;
      a = fmaf(vb[k], (float)W[k * 16 + jj], a);
    }
    a += __shfl_xor(a, 16);
    a += __shfl_xor(a, 32);
    a += (float)Bb[jj];
    float m1 = fmaxf(a, __shfl_xor(a, 1));
    float mx = fmaxf(m1, __shfl_xor(m1, 2));
    float ex = __expf(a - mx);
    float sx = ex + __shfl_xor(ex, 1);
    float sm = sx + __shfl_xor(sx, 2);
    float wv = ex / sm;
    if (lane < 16) { fl[foff + jj] = wv; wbuf[(size_t)b * 52 + foff + jj] = wv; }
    __syncthreads();
  };

  auto cond_phase = [&](const bf16_t* W, const bf16_t* Bb, int tcount) {
    float a4[4];
    bf16x4 bb = *reinterpret_cast<const bf16x4*>(Bb + lane * 4);
#pragma unroll
    for (int e = 0; e < 4; ++e) a4[e] = (float)bb[e];
    for (int t = 0; t < tcount; ++t) {
      float f = fl[t];
      bf16x4 wv = *reinterpret_cast<const bf16x4*>(W + t * 256 + lane * 4);
#pragma unroll
      for (int e = 0; e < 4; ++e) a4[e] = fmaf(f, (float)wv[e], a4[e]);
    }
#pragma unroll
    for (int e = 0; e < 4; ++e) vb[lane * 4 + e] = fmaxf(a4[e] * e4[e], 0.f);
    __syncthreads();
  };

  gw_phase(gw0_w, gw0_b, 0);
  cond_phase(c1_w, c1_b, 16);
  gw_phase(gw1_w, gw1_b, 16);
  cond_phase(c2_w, c2_b, 32);
  gw_phase(gw2_w, gw2_b, 32);
  cond_phase(cL_w, cL_b, 48);
  {
    const int j4 = lane & 3, h16 = lane >> 2;
    float a = 0.f;
    for (int kk = 0; kk < 16; ++kk) {
      int k = h16 * 16 + kk;
      a = fmaf(vb[k], (float)gwL_w[k * 4 + j4], a);
    }
    a += __shfl_xor(a, 4);
    a += __shfl_xor(a, 8);
    a += __shfl_xor(a, 16);
    a += __shfl_xor(a, 32);
    a += (float)gwL_b[j4];
    float m1 = fmaxf(a, __shfl_xor(a, 1));
    float mx = fmaxf(m1, __shfl_xor(m1, 2));
    float ex = __expf(a - mx);
    float sx = ex + __shfl_xor(ex, 1);
    float sm = sx + __shfl_xor(sx, 2);
    if (lane < 4) wbuf[(size_t)b * 52 + 48 + j4] = ex / sm;
  }
}

// ------------- final: BN2-affine, last_weight mix, relu, @last_w + last_b ----
__global__ __launch_bounds__(256) void k_final(
    const bf16_t* __restrict__ mo, const float* __restrict__ s2v, const float* __restrict__ t2v,
    const float* __restrict__ wbuf, const bf16_t* __restrict__ last_w,
    const bf16_t* __restrict__ last_b, void* __restrict__ outv,
    const int* __restrict__ flag)
{
  const int f32out = flag[0];
  const int wave = threadIdx.x >> 6, lane = threadIdx.x & 63;
  const int d0 = lane * 8;
  float sx[4][8], tx[4][8];
  if (lane < 52) {
#pragma unroll
    for (int k = 0; k < 4; ++k)
#pragma unroll
      for (int e = 0; e < 8; ++e) {
        sx[k][e] = s2v[k * DHP_ + d0 + e];
        tx[k][e] = t2v[k * DHP_ + d0 + e];
      }
  }
  for (int b = blockIdx.x * 4 + wave; b < BN_; b += gridDim.x * 4) {
    const float* lwp = wbuf + (size_t)b * 52 + 48;
    float lm0 = lwp[0], lm1 = lwp[1], lm2 = lwp[2], lm3 = lwp[3];
    float slm = lm0 + lm1 + lm2 + lm3;
    const float* w0p = wbuf + (size_t)b * 52;
    float sw0 = w0p[0] + w0p[1] + w0p[2] + w0p[3];
    float p[8];
#pragma unroll
    for (int j = 0; j < 8; ++j) p[j] = 0.f;
    if (lane < 52) {
      float x[4][8];
#pragma unroll
      for (int k = 0; k < 4; ++k) {
        bf16x8 v = *reinterpret_cast<const bf16x8*>(mo + ((size_t)b * MM_ + k) * DHP_ + d0);
#pragma unroll
        for (int e = 0; e < 8; ++e)
          x[k][e] = (float)v[e] * sx[k][e] + tx[k][e];
      }
#pragma unroll
      for (int e = 0; e < 8; ++e) {
        float v = fmaxf(x[0][e] * lm0 + x[1][e] * lm1 + x[2][e] * lm2 + x[3][e] * lm3, 0.f);
        bf16x8 wv = *reinterpret_cast<const bf16x8*>(last_w + (size_t)(d0 + e) * 8);
#pragma unroll
        for (int j = 0; j < 8; ++j) p[j] = fmaf(v, (float)wv[j], p[j]);
      }
    }
#pragma unroll
    for (int j = 0; j < 8; ++j) {
      p[j] += __shfl_xor(p[j], 1);
      p[j] += __shfl_xor(p[j], 2);
      p[j] += __shfl_xor(p[j], 4);
      p[j] += __shfl_xor(p[j], 8);
      p[j] += __shfl_xor(p[j], 16);
      p[j] += __shfl_xor(p[j], 32);
    }
    float sel = p[0];
#pragma unroll
    for (int j = 1; j < 8; ++j) if (lane == j) sel = p[j];
    if (lane < 8) {
      float res = sel + (float)last_b[lane];
      if (!(fabsf(res) < 1e4f)) res = 400.f;
      if (!(slm > 0.97f && slm < 1.03f)) res = 1000.f;
      if (!(sw0 > 0.97f && sw0 < 1.03f)) res = 2000.f;
      if (f32out) ((float*)outv)[(size_t)b * 8 + lane] = res;
      else ((bf16_t*)outv)[(size_t)b * 8 + lane] = (bf16_t)res;
    }
  }
}

// ======================================================================
extern "C" void kernel_launch(void* const* d_in, const int* in_sizes, int n_in,
                              void* d_out, int out_size, void* d_ws, size_t ws_size,
                              hipStream_t stream)
{
  (void)in_sizes; (void)n_in;
  const void* x_raw   = d_in[0];
  const void* emb_raw = d_in[1];
  const void* base_w1 = d_in[2];
  const void* base_w2 = d_in[4];
  const void* em_w    = d_in[6];
  const void* gfc_w1  = d_in[8];
  const void* gfc_w2  = d_in[10];

  char* base = (char*)d_ws;
  size_t off = 0;
  auto alloc = [&](size_t bytes) -> char* {
    off = (off + 255) & ~(size_t)255;
    char* r = base + off; off += bytes; return r;
  };
  int*    dflag = (int*)   alloc(16);
  int*    layC  = (int*)   alloc(16);
  bf16_t* Wt1  = (bf16_t*)alloc((size_t)512 * 128 * 2);
  bf16_t* Wem  = (bf16_t*)alloc((size_t)512 * 64 * 2);
  bf16_t* Wt2  = (bf16_t*)alloc((size_t)512 * DHP_ * 2);
  bf16_t* Wg1  = (bf16_t*)alloc((size_t)256 * DHP_ * 2);
  bf16_t* Wg2  = (bf16_t*)alloc((size_t)256 * 256 * 2);
  bf16_t* WtM  = (bf16_t*)alloc((size_t)MM_ * DHA_ * DHP_ * 2);
  float*  bM   = (float*) alloc((size_t)MM_ * DHA_ * 4);
  bf16_t* xc   = (bf16_t*)alloc((size_t)BN_ * DIN_ * 2);
  bf16_t* embc = (bf16_t*)alloc((size_t)BN_ * DEM_ * 2);
  bf16_t* modWc= (bf16_t*)alloc((size_t)4 * MM_ * DH_ * DH_ * 2);
  bf16_t* out1 = (bf16_t*)alloc((size_t)BN_ * DHP_ * 2);
  bf16_t* emb0 = (bf16_t*)alloc((size_t)BN_ * DHP_ * 2);
  bf16_t* outA = (bf16_t*)alloc((size_t)BN_ * DHP_ * 2);
  bf16_t* emb1 = (bf16_t*)alloc((size_t)BN_ * DHP_ * 2);
  float*  embF = (float*) alloc((size_t)BN_ * GH_ * 4);
  float*  wbuf = (float*) alloc((size_t)BN_ * 52 * 4);
  bf16_t* mo   = (bf16_t*)alloc((size_t)BN_ * MM_ * DHP_ * 2);
  bf16_t* mi   = (bf16_t*)alloc((size_t)BN_ * MM_ * DHP_ * 2);
  float* psA = (float*)alloc((size_t)64 * MM_ * DHP_ * 4);
  float* pqA = (float*)alloc((size_t)64 * MM_ * DHP_ * 4);
  float* psB = (float*)alloc((size_t)64 * MM_ * DHP_ * 4);
  float* pqB = (float*)alloc((size_t)64 * MM_ * DHP_ * 4);
  float* s1 = (float*)alloc((size_t)MM_ * DHP_ * 4);
  float* t1 = (float*)alloc((size_t)MM_ * DHP_ * 4);
  float* s2 = (float*)alloc((size_t)MM_ * DHP_ * 4);
  float* t2 = (float*)alloc((size_t)MM_ * DHP_ * 4);
  const int NS = 26;
  const int sn[NS] = {400, 400, 400, 256, 256,
                      4096, 16, 4096, 256, 4096, 16, 8192, 256, 4096, 16,
                      12288, 256, 1024, 4,
                      6400, 6400, 6400, 6400, 6400, 3200, 8};
  const int si[NS] = {3, 5, 7, 9, 11,
                      12, 13, 14, 15, 16, 17, 18, 19, 20, 21,
                      22, 23, 24, 25,
                      26, 27, 29, 30, 31, 32, 33};
  bf16_t* sc[NS];
  for (int i = 0; i < NS; ++i) sc[i] = (bf16_t*)alloc((size_t)sn[i] * 2);
  bf16_t *b1c = sc[0], *b2c = sc[1], *embbc = sc[2], *g1bc = sc[3], *g2bc = sc[4];
  bf16_t *gw0w = sc[5], *gw0b = sc[6], *c1w = sc[7], *c1b = sc[8], *gw1w = sc[9],
         *gw1b = sc[10], *c2w = sc[11], *c2b = sc[12], *gw2w = sc[13], *gw2b = sc[14],
         *cLw = sc[15], *cLb = sc[16], *gwLw = sc[17], *gwLb = sc[18];
  bf16_t *bn1g = sc[19], *bn1b = sc[20], *modbc = sc[21], *bn2g = sc[22], *bn2b = sc[23];
  bf16_t *lastw = sc[24], *lastb = sc[25];

  if (off > ws_size) {
    hipMemsetAsync(d_out, 0, (size_t)out_size * 2, stream);
    return;
  }

  dim3 blk(256);
  k_detect<<<1, blk, 0, stream>>>((const unsigned*)x_raw, dflag);
  k_mfmaprobe<<<1, dim3(64), 0, stream>>>(layC);

  k_convert<<<dim3(2048), blk, 0, stream>>>(x_raw,   xc,    BN_ * DIN_, dflag);
  k_convert<<<dim3(1024), blk, 0, stream>>>(emb_raw, embc,  BN_ * DEM_, dflag);
  k_convert<<<dim3(2048), blk, 0, stream>>>(d_in[28], modWc, 4 * MM_ * DH_ * DH_, dflag);
  SmallTab tab;
  for (int i = 0; i < NS; ++i) { tab.src[i] = d_in[si[i]]; tab.dst[i] = sc[i]; tab.n[i] = sn[i]; }
  k_convert_smalls<<<dim3(NS), blk, 0, stream>>>(tab, dflag);

  // weight transposes (tiled, padded, zero-filled)
  k_transT<false><<<dim3(2, 8, 1), blk, 0, stream>>>(base_w1, 0, Wt1, 0, DIN_, DH_, 128, 512, nullptr, dflag);
  k_transT<false><<<dim3(1, 8, 1), blk, 0, stream>>>(em_w,    0, Wem, 0, DEM_, DH_, 64, 512, nullptr, dflag);
  k_transT<false><<<dim3(7, 8, 1), blk, 0, stream>>>(base_w2, 0, Wt2, 0, DH_, DH_, DHP_, 512, nullptr, dflag);
  k_transT<false><<<dim3(7, 4, 1), blk, 0, stream>>>(gfc_w1,  0, Wg1, 0, DH_, GH_, DHP_, GH_, nullptr, dflag);
  k_transT<false><<<dim3(4, 4, 1), blk, 0, stream>>>(gfc_w2,  0, Wg2, 0, GH_, GH_, GH_, GH_, nullptr, dflag);

  // front MLPs
  k_gemm_bias<4,  true , false><<<dim3(128, 4), blk, 0, stream>>>(xc, DIN_, Wt1, 128, b1c, DH_, out1, DHP_, DHP_, layC);
  k_gemm_bias<2,  false, false><<<dim3(128, 4), blk, 0, stream>>>(embc, DEM_, Wem, 64, embbc, DH_, emb0, DHP_, DHP_, layC);
  k_gemm_base2<<<dim3(128, 4), blk, 0, stream>>>(out1, Wt2, b2c, emb0, outA, emb1, layC);
  bf16_t* emb2 = emb0;  // emb0 dead after base2 -> reuse
  k_gemm_bias<13, true , false><<<dim3(128, 2), blk, 0, stream>>>(emb1, DHP_, Wg1, DHP_, g1bc, GH_, emb2, GH_, GH_, layC);
  k_gemm_bias<8,  false, true ><<<dim3(128, 2), blk, 0, stream>>>(emb2, GH_, Wg2, GH_, g2bc, GH_, embF, GH_, GH_, layC);

  // gating cascade
  k_gate<<<dim3(BN_ / 4), blk, 0, stream>>>(embF,
      gw0w, gw0b, c1w, c1b, gw1w, gw1b, c2w, c2b, gw2w, gw2b,
      cLw, cLb, gwLw, gwLb, wbuf);

  // layer 0
  k_stats<<<dim3(1, 64), blk, 0, stream>>>(outA, 1, psA, pqA);
  k_bnprep<<<dim3(7), blk, 0, stream>>>(psA, pqA, 0, bn1g, bn1b, s1, t1);
  k_transT<true><<<dim3(7, 8, 4), blk, 0, stream>>>(modWc, (size_t)DH_ * DH_, WtM, (size_t)DHA_ * DHP_,
                                                    DH_, DH_, DHP_, DHA_, s1, nullptr);
  k_foldB<<<dim3(4, 7), blk, 0, stream>>>(modWc, modbc, t1, bM);
  k_gemm_mod<<<dim3(128, 4, 4), blk, 0, stream>>>(outA, DHP_, 0, WtM, bM, mo, layC);
  k_stats<<<dim3(4, 64), blk, 0, stream>>>(mo, MM_, psB, pqB);

  // layers 1..3
  for (int L = 1; L < 4; ++L) {
    k_bnprep<<<dim3(7), blk, 0, stream>>>(psB, pqB, 1,
        bn2g + (size_t)(L - 1) * MM_ * DH_, bn2b + (size_t)(L - 1) * MM_ * DH_, s2, t2);
    k_mix<<<dim3(1024), blk, 0, stream>>>(mo, s2, t2, wbuf, (L - 1) * 16, mi);
    k_stats<<<dim3(4, 64), blk, 0, stream>>>(mi, MM_, psA, pqA);
    k_bnprep<<<dim3(7), blk, 0, stream>>>(psA, pqA, 1,
        bn1g + (size_t)L * MM_ * DH_, bn1b + (size_t)L * MM_ * DH_, s1, t1);
    k_transT<true><<<dim3(7, 8, 4), blk, 0, stream>>>(modWc + (size_t)L * MM_ * DH_ * DH_, (size_t)DH_ * DH_,
                                                      WtM, (size_t)DHA_ * DHP_, DH_, DH_, DHP_, DHA_, s1, nullptr);
    k_foldB<<<dim3(4, 7), blk, 0, stream>>>(modWc + (size_t)L * MM_ * DH_ * DH_, modbc + (size_t)L * MM_ * DH_, t1, bM);
    k_gemm_mod<<<dim3(128, 4, 4), blk, 0, stream>>>(mi, MM_ * DHP_, DHP_, WtM, bM, mo, layC);
    k_stats<<<dim3(4, 64), blk, 0, stream>>>(mo, MM_, psB, pqB);
  }

  // final
  k_bnprep<<<dim3(7), blk, 0, stream>>>(psB, pqB, 1,
      bn2g + (size_t)3 * MM_ * DH_, bn2b + (size_t)3 * MM_ * DH_, s2, t2);
  k_final<<<dim3(1024), blk, 0, stream>>>(mo, s2, t2, wbuf, lastw, lastb, d_out, dflag);
}

// Round 5
// 1023.495 us; speedup vs baseline: 2.1996x; 1.0209x over previous
//
#include <hip/hip_runtime.h>
#include <hip/hip_bf16.h>

typedef __bf16 bf16_t;
typedef __bf16 bf16x8 __attribute__((ext_vector_type(8)));
typedef __bf16 bf16x4 __attribute__((ext_vector_type(4)));
typedef float  f32x4  __attribute__((ext_vector_type(4)));

#define BN_   16384
#define DIN_  128
#define DEM_  64
#define DH_   400
#define DHP_  416   // K padded to 32-multiple
#define DHA_  512   // N padded to 128-tile coverage
#define GH_   256
#define MM_   4
#define EPS_  1e-5f
#define PCOLS 448   // partial-stats column stride
#define NCH   128   // partial-stats chunks

// ---------------- dtype detector: low-16 of f32 words decodes to garbage bf16
__global__ __launch_bounds__(256) void k_detect(const unsigned* __restrict__ w,
                                                int* __restrict__ flag)
{
  __shared__ int cnt[256];
  int c = 0;
  for (int i = 0; i < 16; ++i) {
    unsigned v = w[threadIdx.x * 16 + i];
    float lo = __uint_as_float((v & 0xffffu) << 16);
    if (!(fabsf(lo) < 1e4f)) ++c;
  }
  cnt[threadIdx.x] = c;
  __syncthreads();
  if (threadIdx.x == 0) {
    int t = 0;
    for (int i = 0; i < 256; ++i) t += cnt[i];
    flag[0] = (t > 64) ? 1 : 0;     // 1 = inputs are float32
  }
}

// ---------------- MFMA C/D layout probe
__global__ void k_mfmaprobe(int* __restrict__ layC)
{
  int l = threadIdx.x & 63;
  bf16x8 av, bv;
#pragma unroll
  for (int e = 0; e < 8; ++e) { av[e] = (bf16_t)0.f; bv[e] = (bf16_t)0.f; }
  if ((l >> 4) == 0) av[0] = (bf16_t)(float)(l & 15);
  if (l == 0)        bv[0] = (bf16_t)1.f;
  f32x4 acc = {0.f, 0.f, 0.f, 0.f};
  acc = __builtin_amdgcn_mfma_f32_16x16x32_bf16(av, bv, acc, 0, 0, 0);
  if (l == 1) layC[0] = (acc[0] > 0.5f) ? 1 : 0;
}

// ---------------- dtype-agnostic converters ---------------------------------
__global__ __launch_bounds__(256) void k_convert(
    const void* __restrict__ src, bf16_t* __restrict__ dst, int n,
    const int* __restrict__ flag)
{
  const int f = flag[0];
  for (int i = blockIdx.x * 256 + threadIdx.x; i < n; i += gridDim.x * 256)
    dst[i] = f ? (bf16_t)((const float*)src)[i] : ((const bf16_t*)src)[i];
}

struct SmallTab {
  const void* src[26];
  bf16_t*     dst[26];
  int         n[26];
};

__global__ __launch_bounds__(256) void k_convert_smalls(SmallTab tab, const int* __restrict__ flag)
{
  const int f = flag[0];
  const void* s = tab.src[blockIdx.x];
  bf16_t*     d = tab.dst[blockIdx.x];
  const int   n = tab.n[blockIdx.x];
  for (int i = threadIdx.x; i < n; i += 256)
    d[i] = f ? (bf16_t)((const float*)s)[i] : ((const bf16_t*)s)[i];
}

// ---------------- tiled transpose (+optional per-k scale fold), coalesced ----
// dst[z][n][k] = scale[z*DHP_+k] * src[srcOff + z*srcStride + k*N + n]
template<bool SCALED>
__global__ __launch_bounds__(256) void k_transT(
    const void* __restrict__ src, size_t srcOff, size_t srcStride,
    bf16_t* __restrict__ dst, size_t dstStride,
    int K, int N, int KP, int NPa,
    const float* __restrict__ scale, const int* __restrict__ flag)
{
  __shared__ float T[64][65];
  const int f = flag ? flag[0] : 0;
  const int z = blockIdx.z;
  const float*  sf = (const float*) src + srcOff + (size_t)z * srcStride;
  const bf16_t* sb = (const bf16_t*)src + srcOff + (size_t)z * srcStride;
  bf16_t* dp = dst + (size_t)z * dstStride;
  const int k0 = blockIdx.x * 64, n0 = blockIdx.y * 64;
  const int lr = threadIdx.x >> 6, ln = threadIdx.x & 63;
#pragma unroll
  for (int p = 0; p < 16; ++p) {
    int kl = p * 4 + lr;
    int k = k0 + kl, n = n0 + ln;
    float v = 0.f;
    if (k < K && n < N)
      v = f ? sf[(size_t)k * N + n] : (float)sb[(size_t)k * N + n];
    if (SCALED && k < K) v *= scale[z * DHP_ + k];
    T[kl][ln] = v;
  }
  __syncthreads();
#pragma unroll
  for (int p = 0; p < 16; ++p) {
    int nl = p * 4 + lr;
    int n = n0 + nl, k = k0 + ln;
    if (n < NPa && k < KP) dp[(size_t)n * KP + k] = (bf16_t)T[ln][nl];
  }
}

// ---------------------------------------------------------------- GEMM core
template<int KS>
__device__ __forceinline__ void gemm_core(
    const bf16_t* __restrict__ A, int lda,
    const bf16_t* __restrict__ Bt, int ldb,
    int row0, int col0, int rr, int qq,
    f32x4 (&acc)[4][4])
{
  const bf16_t* a0 = A + (size_t)(row0 + rr) * lda + qq * 8;
  const bf16_t* b0 = Bt + (size_t)(col0 + rr) * ldb + qq * 8;
#pragma unroll 2
  for (int ks = 0; ks < KS; ++ks) {
    bf16x8 av[4], bv[4];
#pragma unroll
    for (int i = 0; i < 4; ++i)
      av[i] = *reinterpret_cast<const bf16x8*>(a0 + (size_t)i * 16 * lda);
#pragma unroll
    for (int i = 0; i < 4; ++i)
      bv[i] = *reinterpret_cast<const bf16x8*>(b0 + (size_t)i * 16 * ldb);
#pragma unroll
    for (int i = 0; i < 4; ++i)
#pragma unroll
      for (int j = 0; j < 4; ++j)
        acc[i][j] = __builtin_amdgcn_mfma_f32_16x16x32_bf16(av[i], bv[j], acc[i][j], 0, 0, 0);
    a0 += 32; b0 += 32;
  }
}

__device__ __forceinline__ void acc_zero(f32x4 (&acc)[4][4]) {
  const f32x4 z = {0.f, 0.f, 0.f, 0.f};
#pragma unroll
  for (int i = 0; i < 4; ++i)
#pragma unroll
    for (int j = 0; j < 4; ++j) acc[i][j] = z;
}

// ------------------------------------------------- generic bias(+relu) GEMM
template<int KS, bool RELU, bool OUTF32>
__global__ __launch_bounds__(256) void k_gemm_bias(
    const bf16_t* __restrict__ A, int lda,
    const bf16_t* __restrict__ Bt, int ldb,
    const bf16_t* __restrict__ bias, int nbias,
    void* __restrict__ outv, int ldo, int nout,
    const int* __restrict__ layC)
{
  const int lay = layC[0];
  const int w = threadIdx.x >> 6, lane = threadIdx.x & 63;
  const int rr = lane & 15, qq = lane >> 4;
  const int row0 = blockIdx.x * 128 + (w >> 1) * 64;
  const int col0 = blockIdx.y * 128 + (w & 1) * 64;
  if (col0 >= nout) return;
  f32x4 acc[4][4]; acc_zero(acc);
  gemm_core<KS>(A, lda, Bt, ldb, row0, col0, rr, qq, acc);
#pragma unroll
  for (int j = 0; j < 4; ++j) {
#pragma unroll
    for (int i = 0; i < 4; ++i) {
#pragma unroll
      for (int e = 0; e < 4; ++e) {
        int ri = lay ? rr : qq * 4 + e;
        int ci = lay ? qq * 4 + e : rr;
        int row = row0 + i * 16 + ri;
        int col = col0 + j * 16 + ci;
        if (col >= nout) continue;
        float bv = (col < nbias) ? (float)bias[col] : 0.f;
        float v = acc[i][j][e] + bv;
        if (RELU) v = fmaxf(v, 0.f);
        if (OUTF32) ((float*)outv)[(size_t)row * ldo + col] = v;
        else ((bf16_t*)outv)[(size_t)row * ldo + col] = (bf16_t)v;
      }
    }
  }
}

// ---- base layer 2: outA=relu(A@W2+b2); emb1=relu(emb0*(A@W2+b2)); fused outA stats
__global__ __launch_bounds__(256) void k_gemm_base2(
    const bf16_t* __restrict__ A, const bf16_t* __restrict__ Bt,
    const bf16_t* __restrict__ bias, const bf16_t* __restrict__ emb0,
    bf16_t* __restrict__ outA, bf16_t* __restrict__ emb1,
    float* __restrict__ ps, float* __restrict__ pq,
    const int* __restrict__ layC)
{
  __shared__ float rs[2][128], rq[2][128];
  const int lay = layC[0];
  const int w = threadIdx.x >> 6, lane = threadIdx.x & 63;
  const int rr = lane & 15, qq = lane >> 4;
  const int row0 = blockIdx.x * 128 + (w >> 1) * 64;
  const int col0 = blockIdx.y * 128 + (w & 1) * 64;
  const bool active = (col0 < DHP_);
  f32x4 acc[4][4]; acc_zero(acc);
  if (active) gemm_core<13>(A, DHP_, Bt, DHP_, row0, col0, rr, qq, acc);
  float s[4] = {0.f, 0.f, 0.f, 0.f}, q[4] = {0.f, 0.f, 0.f, 0.f};
  if (active) {
#pragma unroll
    for (int j = 0; j < 4; ++j) {
#pragma unroll
      for (int i = 0; i < 4; ++i) {
#pragma unroll
        for (int e = 0; e < 4; ++e) {
          int ri = lay ? rr : qq * 4 + e;
          int ci = lay ? qq * 4 + e : rr;
          int row = row0 + i * 16 + ri;
          int col = col0 + j * 16 + ci;
          if (col >= DHP_) continue;
          float bv = (col < DH_) ? (float)bias[col] : 0.f;
          float op = acc[i][j][e] + bv;
          float o  = fmaxf(op, 0.f);
          float e0 = (float)emb0[(size_t)row * DHP_ + col];
          float m1 = fmaxf(e0 * op, 0.f);
          outA[(size_t)row * DHP_ + col] = (bf16_t)o;
          emb1[(size_t)row * DHP_ + col] = (bf16_t)m1;
          s[j] += o; q[j] += o * o;
        }
      }
    }
  }
  // fused stats (lay==0 path only; cols of j are uniform then)
#pragma unroll
  for (int j = 0; j < 4; ++j) {
    s[j] += __shfl_xor(s[j], 16); s[j] += __shfl_xor(s[j], 32);
    q[j] += __shfl_xor(q[j], 16); q[j] += __shfl_xor(q[j], 32);
  }
  if (lane < 16) {
#pragma unroll
    for (int j = 0; j < 4; ++j) {
      rs[w >> 1][(w & 1) * 64 + j * 16 + lane] = s[j];
      rq[w >> 1][(w & 1) * 64 + j * 16 + lane] = q[j];
    }
  }
  __syncthreads();
  if (lay == 0 && threadIdx.x < 128) {
    int col = blockIdx.y * 128 + threadIdx.x;
    if (col < PCOLS) {
      ps[((size_t)blockIdx.x * MM_ + 0) * PCOLS + col] = rs[0][threadIdx.x] + rs[1][threadIdx.x];
      pq[((size_t)blockIdx.x * MM_ + 0) * PCOLS + col] = rq[0][threadIdx.x] + rq[1][threadIdx.x];
    }
  }
}

// ---- module GEMM: mo[b][m][:] = A_m[b][:] @ W'_m + b'_m; fused mo stats
__global__ __launch_bounds__(256) void k_gemm_mod(
    const bf16_t* __restrict__ Abase, int lda, int mstride,
    const bf16_t* __restrict__ WtM, const float* __restrict__ bM,
    bf16_t* __restrict__ mo,
    float* __restrict__ ps, float* __restrict__ pq,
    const int* __restrict__ layC)
{
  __shared__ float rs[2][128], rq[2][128];
  const int lay = layC[0];
  const int m = blockIdx.z;
  const int w = threadIdx.x >> 6, lane = threadIdx.x & 63;
  const int rr = lane & 15, qq = lane >> 4;
  const int row0 = blockIdx.x * 128 + (w >> 1) * 64;
  const int col0 = blockIdx.y * 128 + (w & 1) * 64;
  const bool active = (col0 < DHP_);
  f32x4 acc[4][4]; acc_zero(acc);
  if (active)
    gemm_core<13>(Abase + (size_t)m * mstride, lda, WtM + (size_t)m * DHA_ * DHP_, DHP_,
                  row0, col0, rr, qq, acc);
  float s[4] = {0.f, 0.f, 0.f, 0.f}, q[4] = {0.f, 0.f, 0.f, 0.f};
  if (active) {
#pragma unroll
    for (int j = 0; j < 4; ++j) {
#pragma unroll
      for (int i = 0; i < 4; ++i) {
#pragma unroll
        for (int e = 0; e < 4; ++e) {
          int ri = lay ? rr : qq * 4 + e;
          int ci = lay ? qq * 4 + e : rr;
          int row = row0 + i * 16 + ri;
          int col = col0 + j * 16 + ci;
          if (col >= DHP_) continue;
          float v = acc[i][j][e] + bM[m * DHA_ + col];
          mo[((size_t)row * MM_ + m) * DHP_ + col] = (bf16_t)v;
          s[j] += v; q[j] += v * v;
        }
      }
    }
  }
#pragma unroll
  for (int j = 0; j < 4; ++j) {
    s[j] += __shfl_xor(s[j], 16); s[j] += __shfl_xor(s[j], 32);
    q[j] += __shfl_xor(q[j], 16); q[j] += __shfl_xor(q[j], 32);
  }
  if (lane < 16) {
#pragma unroll
    for (int j = 0; j < 4; ++j) {
      rs[w >> 1][(w & 1) * 64 + j * 16 + lane] = s[j];
      rq[w >> 1][(w & 1) * 64 + j * 16 + lane] = q[j];
    }
  }
  __syncthreads();
  if (lay == 0 && threadIdx.x < 128) {
    int col = blockIdx.y * 128 + threadIdx.x;
    if (col < PCOLS) {
      ps[((size_t)blockIdx.x * MM_ + m) * PCOLS + col] = rs[0][threadIdx.x] + rs[1][threadIdx.x];
      pq[((size_t)blockIdx.x * MM_ + m) * PCOLS + col] = rq[0][threadIdx.x] + rq[1][threadIdx.x];
    }
  }
}

// ---------------- stand-alone stats (128-chunk partial layout) ---------------
// GUARDED=true: only runs if lay!=0 (fallback for fused epilogues)
template<bool GUARDED>
__global__ __launch_bounds__(256) void k_stats(
    const bf16_t* __restrict__ src, int nm,
    float* __restrict__ ps, float* __restrict__ pq,
    const int* __restrict__ layC)
{
  if (GUARDED && layC[0] == 0) return;
  __shared__ float lsum[4 * 52 * 8], lsq[4 * 52 * 8];
  const int m = blockIdx.x, ch = blockIdx.y;
  const int sub = threadIdx.x >> 6, lane = threadIdx.x & 63;
  float s[8], q[8];
#pragma unroll
  for (int e = 0; e < 8; ++e) { s[e] = 0.f; q[e] = 0.f; }
  if (lane < 52) {
    for (int i = 0; i < 32; ++i) {
      int b = ch * 128 + sub + i * 4;
      bf16x8 v = *reinterpret_cast<const bf16x8*>(src + ((size_t)b * nm + m) * DHP_ + lane * 8);
#pragma unroll
      for (int e = 0; e < 8; ++e) {
        float f = (float)v[e];
        s[e] += f; q[e] += f * f;
      }
    }
#pragma unroll
    for (int e = 0; e < 8; ++e) {
      lsum[(sub * 52 + lane) * 8 + e] = s[e];
      lsq [(sub * 52 + lane) * 8 + e] = q[e];
    }
  }
  __syncthreads();
  for (int idx = threadIdx.x; idx < 416; idx += 256) {
    float S = lsum[idx] + lsum[416 + idx] + lsum[832 + idx] + lsum[1248 + idx];
    float Q = lsq [idx] + lsq [416 + idx] + lsq [832 + idx] + lsq [1248 + idx];
    ps[((size_t)ch * MM_ + m) * PCOLS + idx] = S;
    pq[((size_t)ch * MM_ + m) * PCOLS + idx] = Q;
  }
}

// ---------------- partials -> BN scale/shift per (m,d) -----------------------
__global__ __launch_bounds__(256) void k_bnprep(
    const float* __restrict__ ps, const float* __restrict__ pq, int per_m,
    const bf16_t* __restrict__ g, const bf16_t* __restrict__ b,
    float* __restrict__ s_o, float* __restrict__ t_o)
{
  int idx = blockIdx.x * 256 + threadIdx.x;
  if (idx >= MM_ * DHP_) return;
  int m = idx / DHP_, k = idx - m * DHP_;
  float s = 0.f, t = 0.f;
  if (k < DH_) {
    int mm = per_m ? m : 0;
    float S = 0.f, Q = 0.f;
    for (int ch = 0; ch < NCH; ++ch) {
      S += ps[((size_t)ch * MM_ + mm) * PCOLS + k];
      Q += pq[((size_t)ch * MM_ + mm) * PCOLS + k];
    }
    float mean = S * (1.f / BN_);
    float var  = fmaxf(Q * (1.f / BN_) - mean * mean, 0.f);
    float rstd = rsqrtf(var + EPS_);
    s = (float)g[m * DH_ + k] * rstd;
    t = (float)b[m * DH_ + k] - mean * s;
  }
  s_o[m * DHP_ + k] = s;
  t_o[m * DHP_ + k] = t;
}

// b'_m[n] = mod_b[m][n] + sum_k shift[m][k]*W[m][k][n]  (reads raw modW)
__global__ __launch_bounds__(256) void k_foldB(
    const void* __restrict__ modW, size_t off, const bf16_t* __restrict__ modb,
    const float* __restrict__ t1v, float* __restrict__ bM,
    const int* __restrict__ flag)
{
  __shared__ float ls[256];
  const int f = flag[0];
  const int m = blockIdx.x, ncg = blockIdx.y;
  const int t = threadIdx.x;
  const int n = ncg * 64 + (t & 63);
  const int ks = t >> 6;
  float a = 0.f;
  if (n < DH_) {
    for (int k = ks * 100; k < ks * 100 + 100; ++k) {
      size_t idx = off + ((size_t)m * DH_ + k) * DH_ + n;
      float wv = f ? ((const float*)modW)[idx] : (float)((const bf16_t*)modW)[idx];
      a += t1v[m * DHP_ + k] * wv;
    }
  }
  ls[t] = a;
  __syncthreads();
  if (t < 64) {
    int nn = ncg * 64 + t;
    float v = ls[t] + ls[t + 64] + ls[t + 128] + ls[t + 192];
    if (nn < DH_) v += (float)modb[m * DH_ + nn];
    else v = 0.f;
    bM[m * DHA_ + nn] = v;
  }
  if (ncg == 6 && t < 64) bM[m * DHA_ + 448 + t] = 0.f;
}

// ---------------- routing mix (wave-per-sample, coalesced) -------------------
__global__ __launch_bounds__(256) void k_mix(
    const bf16_t* __restrict__ mo, const float* __restrict__ s2v, const float* __restrict__ t2v,
    const float* __restrict__ wbuf, int woff, bf16_t* __restrict__ mi)
{
  const int wave = threadIdx.x >> 6, lane = threadIdx.x & 63;
  const int d0 = lane * 8;
  float sx[4][8], tx[4][8];
  if (lane < 52) {
#pragma unroll
    for (int k = 0; k < 4; ++k)
#pragma unroll
      for (int e = 0; e < 8; ++e) {
        sx[k][e] = s2v[k * DHP_ + d0 + e];
        tx[k][e] = t2v[k * DHP_ + d0 + e];
      }
  }
  for (int b = blockIdx.x * 4 + wave; b < BN_; b += gridDim.x * 4) {
    float wv = (lane < 16) ? wbuf[(size_t)b * 52 + woff + lane] : 0.f;
    if (lane < 52) {
      float x[4][8];
#pragma unroll
      for (int k = 0; k < 4; ++k) {
        bf16x8 v = *reinterpret_cast<const bf16x8*>(mo + ((size_t)b * MM_ + k) * DHP_ + d0);
#pragma unroll
        for (int e = 0; e < 8; ++e)
          x[k][e] = (float)v[e] * sx[k][e] + tx[k][e];
      }
#pragma unroll
      for (int j = 0; j < 4; ++j) {
        float w0 = __shfl(wv, j * 4 + 0), w1 = __shfl(wv, j * 4 + 1);
        float w2 = __shfl(wv, j * 4 + 2), w3 = __shfl(wv, j * 4 + 3);
        bf16x8 ov;
#pragma unroll
        for (int e = 0; e < 8; ++e) {
          float a = x[0][e] * w0 + x[1][e] * w1 + x[2][e] * w2 + x[3][e] * w3;
          ov[e] = (bf16_t)fmaxf(a, 0.f);
        }
        *reinterpret_cast<bf16x8*>(mi + ((size_t)b * MM_ + j) * DHP_ + d0) = ov;
      }
    }
  }
}

// --------------------------- gating cascade v3 -------------------------------
// transposed gw weights, padded LDS (conflict-free), vectorized loads
__global__ __launch_bounds__(256) void k_gate(
    const float* __restrict__ emb,
    const bf16_t* __restrict__ gw0t, const bf16_t* __restrict__ gw0_b,
    const bf16_t* __restrict__ c1_w,  const bf16_t* __restrict__ c1_b,
    const bf16_t* __restrict__ gw1t, const bf16_t* __restrict__ gw1_b,
    const bf16_t* __restrict__ c2_w,  const bf16_t* __restrict__ c2_b,
    const bf16_t* __restrict__ gw2t, const bf16_t* __restrict__ gw2_b,
    const bf16_t* __restrict__ cL_w,  const bf16_t* __restrict__ cL_b,
    const bf16_t* __restrict__ gwLt, const bf16_t* __restrict__ gwL_b,
    float* __restrict__ wbuf)
{
  __shared__ float VBUF[4][272];    // +4 pad per 64-float chunk: idx = k + (k>>6)*4
  __shared__ float FLAT[4][64];
  const int wave = threadIdx.x >> 6, lane = threadIdx.x & 63;
  const int b = blockIdx.x * 4 + wave;
  float* vb = VBUF[wave];
  float* fl = FLAT[wave];
  const int wrIdx = lane * 4 + (lane >> 4) * 4;   // padded, 16B-aligned

  float e4[4];
  {
    f32x4 ev = *reinterpret_cast<const f32x4*>(emb + (size_t)b * GH_ + lane * 4);
    f32x4 rv;
#pragma unroll
    for (int e = 0; e < 4; ++e) { e4[e] = ev[e]; rv[e] = fmaxf(ev[e], 0.f); }
    *reinterpret_cast<f32x4*>(vb + wrIdx) = rv;
  }
  __syncthreads();

  const int hh = lane >> 4, jj = lane & 15;

  auto gw_phase = [&](const bf16_t* Wt, const bf16_t* Bb, int foff) {
    float a = 0.f;
#pragma unroll
    for (int cc = 0; cc < 8; ++cc) {
      int c8 = (cc + hh * 2) & 7;
      int k  = hh * 64 + c8 * 8;
      int idx = k + hh * 4;
      f32x4 v0 = *reinterpret_cast<const f32x4*>(vb + idx);
      f32x4 v1 = *reinterpret_cast<const f32x4*>(vb + idx + 4);
      bf16x8 wv = *reinterpret_cast<const bf16x8*>(Wt + jj * 256 + k);
      a = fmaf(v0[0], (float)wv[0], a);
      a = fmaf(v0[1], (float)wv[1], a);
      a = fmaf(v0[2], (float)wv[2], a);
      a = fmaf(v0[3], (float)wv[3], a);
      a = fmaf(v1[0], (float)wv[4], a);
      a = fmaf(v1[1], (float)wv[5], a);
      a = fmaf(v1[2], (float)wv[6], a);
      a = fmaf(v1[3], (float)wv[7], a);
    }
    a += __shfl_xor(a, 16);
    a += __shfl_xor(a, 32);
    a += (float)Bb[jj];
    float m1 = fmaxf(a, __shfl_xor(a, 1));
    float mx = fmaxf(m1, __shfl_xor(m1, 2));
    float ex = __expf(a - mx);
    float sx = ex + __shfl_xor(ex, 1);
    float sm = sx + __shfl_xor(sx, 2);
    float wv = ex / sm;
    if (lane < 16) { fl[foff + jj] = wv; wbuf[(size_t)b * 52 + foff + jj] = wv; }
    __syncthreads();
  };

  auto cond_phase = [&](const bf16_t* W, const bf16_t* Bb, int tcount) {
    float a4[4];
    bf16x4 bb = *reinterpret_cast<const bf16x4*>(Bb + lane * 4);
#pragma unroll
    for (int e = 0; e < 4; ++e) a4[e] = (float)bb[e];
    for (int t = 0; t < tcount; ++t) {
      float f = fl[t];
      bf16x4 wv = *reinterpret_cast<const bf16x4*>(W + t * 256 + lane * 4);
#pragma unroll
      for (int e = 0; e < 4; ++e) a4[e] = fmaf(f, (float)wv[e], a4[e]);
    }
    f32x4 rv;
#pragma unroll
    for (int e = 0; e < 4; ++e) rv[e] = fmaxf(a4[e] * e4[e], 0.f);
    *reinterpret_cast<f32x4*>(vb + wrIdx) = rv;
    __syncthreads();
  };

  gw_phase(gw0t, gw0_b, 0);
  cond_phase(c1_w, c1_b, 16);
  gw_phase(gw1t, gw1_b, 16);
  cond_phase(c2_w, c2_b, 32);
  gw_phase(gw2t, gw2_b, 32);
  cond_phase(cL_w, cL_b, 48);
  {
    const int j4 = lane & 3, h16 = lane >> 2;
    const int base = h16 * 16 + (h16 >> 2) * 4;
    bf16x8 w0 = *reinterpret_cast<const bf16x8*>(gwLt + j4 * 256 + h16 * 16);
    bf16x8 w1 = *reinterpret_cast<const bf16x8*>(gwLt + j4 * 256 + h16 * 16 + 8);
    float a = 0.f;
#pragma unroll
    for (int c = 0; c < 2; ++c) {
      f32x4 v0 = *reinterpret_cast<const f32x4*>(vb + base + c * 8);
      f32x4 v1 = *reinterpret_cast<const f32x4*>(vb + base + c * 8 + 4);
      const bf16x8& w = c ? w1 : w0;
      a = fmaf(v0[0], (float)w[0], a);
      a = fmaf(v0[1], (float)w[1], a);
      a = fmaf(v0[2], (float)w[2], a);
      a = fmaf(v0[3], (float)w[3], a);
      a = fmaf(v1[0], (float)w[4], a);
      a = fmaf(v1[1], (float)w[5], a);
      a = fmaf(v1[2], (float)w[6], a);
      a = fmaf(v1[3], (float)w[7], a);
    }
    a += __shfl_xor(a, 4);
    a += __shfl_xor(a, 8);
    a += __shfl_xor(a, 16);
    a += __shfl_xor(a, 32);
    a += (float)gwL_b[j4];
    float m1 = fmaxf(a, __shfl_xor(a, 1));
    float mx = fmaxf(m1, __shfl_xor(m1, 2));
    float ex = __expf(a - mx);
    float sx = ex + __shfl_xor(ex, 1);
    float sm = sx + __shfl_xor(sx, 2);
    if (lane < 4) wbuf[(size_t)b * 52 + 48 + j4] = ex / sm;
  }
}

// ------------- final: BN2-affine, last_weight mix, relu, @last_w + last_b ----
__global__ __launch_bounds__(256) void k_final(
    const bf16_t* __restrict__ mo, const float* __restrict__ s2v, const float* __restrict__ t2v,
    const float* __restrict__ wbuf, const bf16_t* __restrict__ last_w,
    const bf16_t* __restrict__ last_b, void* __restrict__ outv,
    const int* __restrict__ flag)
{
  const int f32out = flag[0];
  const int wave = threadIdx.x >> 6, lane = threadIdx.x & 63;
  const int d0 = lane * 8;
  float sx[4][8], tx[4][8];
  if (lane < 52) {
#pragma unroll
    for (int k = 0; k < 4; ++k)
#pragma unroll
      for (int e = 0; e < 8; ++e) {
        sx[k][e] = s2v[k * DHP_ + d0 + e];
        tx[k][e] = t2v[k * DHP_ + d0 + e];
      }
  }
  for (int b = blockIdx.x * 4 + wave; b < BN_; b += gridDim.x * 4) {
    const float* lwp = wbuf + (size_t)b * 52 + 48;
    float lm0 = lwp[0], lm1 = lwp[1], lm2 = lwp[2], lm3 = lwp[3];
    float slm = lm0 + lm1 + lm2 + lm3;
    const float* w0p = wbuf + (size_t)b * 52;
    float sw0 = w0p[0] + w0p[1] + w0p[2] + w0p[3];
    float p[8];
#pragma unroll
    for (int j = 0; j < 8; ++j) p[j] = 0.f;
    if (lane < 52) {
      float x[4][8];
#pragma unroll
      for (int k = 0; k < 4; ++k) {
        bf16x8 v = *reinterpret_cast<const bf16x8*>(mo + ((size_t)b * MM_ + k) * DHP_ + d0);
#pragma unroll
        for (int e = 0; e < 8; ++e)
          x[k][e] = (float)v[e] * sx[k][e] + tx[k][e];
      }
#pragma unroll
      for (int e = 0; e < 8; ++e) {
        float v = fmaxf(x[0][e] * lm0 + x[1][e] * lm1 + x[2][e] * lm2 + x[3][e] * lm3, 0.f);
        bf16x8 wv = *reinterpret_cast<const bf16x8*>(last_w + (size_t)(d0 + e) * 8);
#pragma unroll
        for (int j = 0; j < 8; ++j) p[j] = fmaf(v, (float)wv[j], p[j]);
      }
    }
#pragma unroll
    for (int j = 0; j < 8; ++j) {
      p[j] += __shfl_xor(p[j], 1);
      p[j] += __shfl_xor(p[j], 2);
      p[j] += __shfl_xor(p[j], 4);
      p[j] += __shfl_xor(p[j], 8);
      p[j] += __shfl_xor(p[j], 16);
      p[j] += __shfl_xor(p[j], 32);
    }
    float sel = p[0];
#pragma unroll
    for (int j = 1; j < 8; ++j) if (lane == j) sel = p[j];
    if (lane < 8) {
      float res = sel + (float)last_b[lane];
      if (!(fabsf(res) < 1e4f)) res = 400.f;
      if (!(slm > 0.97f && slm < 1.03f)) res = 1000.f;
      if (!(sw0 > 0.97f && sw0 < 1.03f)) res = 2000.f;
      if (f32out) ((float*)outv)[(size_t)b * 8 + lane] = res;
      else ((bf16_t*)outv)[(size_t)b * 8 + lane] = (bf16_t)res;
    }
  }
}

// ======================================================================
extern "C" void kernel_launch(void* const* d_in, const int* in_sizes, int n_in,
                              void* d_out, int out_size, void* d_ws, size_t ws_size,
                              hipStream_t stream)
{
  (void)in_sizes; (void)n_in;
  const void* x_raw   = d_in[0];
  const void* emb_raw = d_in[1];
  const void* base_w1 = d_in[2];
  const void* base_w2 = d_in[4];
  const void* em_w    = d_in[6];
  const void* gfc_w1  = d_in[8];
  const void* gfc_w2  = d_in[10];
  const void* modW_raw= d_in[28];

  char* base = (char*)d_ws;
  size_t off = 0;
  auto alloc = [&](size_t bytes) -> char* {
    off = (off + 255) & ~(size_t)255;
    char* r = base + off; off += bytes; return r;
  };
  int*    dflag = (int*)   alloc(16);
  int*    layC  = (int*)   alloc(16);
  bf16_t* Wt1  = (bf16_t*)alloc((size_t)512 * 128 * 2);
  bf16_t* Wem  = (bf16_t*)alloc((size_t)512 * 64 * 2);
  bf16_t* Wt2  = (bf16_t*)alloc((size_t)512 * DHP_ * 2);
  bf16_t* Wg1  = (bf16_t*)alloc((size_t)256 * DHP_ * 2);
  bf16_t* Wg2  = (bf16_t*)alloc((size_t)256 * 256 * 2);
  bf16_t* WtM  = (bf16_t*)alloc((size_t)MM_ * DHA_ * DHP_ * 2);
  float*  bM   = (float*) alloc((size_t)MM_ * DHA_ * 4);
  bf16_t* xc   = (bf16_t*)alloc((size_t)BN_ * DIN_ * 2);
  bf16_t* embc = (bf16_t*)alloc((size_t)BN_ * DEM_ * 2);
  bf16_t* out1 = (bf16_t*)alloc((size_t)BN_ * DHP_ * 2);
  bf16_t* emb0 = (bf16_t*)alloc((size_t)BN_ * DHP_ * 2);
  bf16_t* outA = (bf16_t*)alloc((size_t)BN_ * DHP_ * 2);
  bf16_t* emb1 = (bf16_t*)alloc((size_t)BN_ * DHP_ * 2);
  float*  embF = (float*) alloc((size_t)BN_ * GH_ * 4);
  float*  wbuf = (float*) alloc((size_t)BN_ * 52 * 4);
  bf16_t* mo   = (bf16_t*)alloc((size_t)BN_ * MM_ * DHP_ * 2);
  bf16_t* mi   = (bf16_t*)alloc((size_t)BN_ * MM_ * DHP_ * 2);
  float* psO = (float*)alloc((size_t)NCH * MM_ * PCOLS * 4);
  float* pqO = (float*)alloc((size_t)NCH * MM_ * PCOLS * 4);
  float* psA = (float*)alloc((size_t)NCH * MM_ * PCOLS * 4);
  float* pqA = (float*)alloc((size_t)NCH * MM_ * PCOLS * 4);
  float* psB = (float*)alloc((size_t)NCH * MM_ * PCOLS * 4);
  float* pqB = (float*)alloc((size_t)NCH * MM_ * PCOLS * 4);
  float* s1 = (float*)alloc((size_t)MM_ * DHP_ * 4);
  float* t1 = (float*)alloc((size_t)MM_ * DHP_ * 4);
  float* s2 = (float*)alloc((size_t)MM_ * DHP_ * 4);
  float* t2 = (float*)alloc((size_t)MM_ * DHP_ * 4);
  bf16_t* gw0t = (bf16_t*)alloc((size_t)16 * 256 * 2);
  bf16_t* gw1t = (bf16_t*)alloc((size_t)16 * 256 * 2);
  bf16_t* gw2t = (bf16_t*)alloc((size_t)16 * 256 * 2);
  bf16_t* gwLt = (bf16_t*)alloc((size_t)4 * 256 * 2);
  const int NS = 26;
  const int sn[NS] = {400, 400, 400, 256, 256,
                      4096, 16, 4096, 256, 4096, 16, 8192, 256, 4096, 16,
                      12288, 256, 1024, 4,
                      6400, 6400, 6400, 6400, 6400, 3200, 8};
  const int si[NS] = {3, 5, 7, 9, 11,
                      12, 13, 14, 15, 16, 17, 18, 19, 20, 21,
                      22, 23, 24, 25,
                      26, 27, 29, 30, 31, 32, 33};
  bf16_t* sc[NS];
  for (int i = 0; i < NS; ++i) sc[i] = (bf16_t*)alloc((size_t)sn[i] * 2);
  bf16_t *b1c = sc[0], *b2c = sc[1], *embbc = sc[2], *g1bc = sc[3], *g2bc = sc[4];
  bf16_t *gw0w = sc[5], *gw0b = sc[6], *c1w = sc[7], *c1b = sc[8], *gw1w = sc[9],
         *gw1b = sc[10], *c2w = sc[11], *c2b = sc[12], *gw2w = sc[13], *gw2b = sc[14],
         *cLw = sc[15], *cLb = sc[16], *gwLw = sc[17], *gwLb = sc[18];
  bf16_t *bn1g = sc[19], *bn1b = sc[20], *modbc = sc[21], *bn2g = sc[22], *bn2b = sc[23];
  bf16_t *lastw = sc[24], *lastb = sc[25];

  if (off > ws_size) {
    hipMemsetAsync(d_out, 0, (size_t)out_size * 2, stream);
    return;
  }

  dim3 blk(256);
  k_detect<<<1, blk, 0, stream>>>((const unsigned*)x_raw, dflag);
  k_mfmaprobe<<<1, dim3(64), 0, stream>>>(layC);

  k_convert<<<dim3(2048), blk, 0, stream>>>(x_raw,   xc,    BN_ * DIN_, dflag);
  k_convert<<<dim3(1024), blk, 0, stream>>>(emb_raw, embc,  BN_ * DEM_, dflag);
  SmallTab tab;
  for (int i = 0; i < NS; ++i) { tab.src[i] = d_in[si[i]]; tab.dst[i] = sc[i]; tab.n[i] = sn[i]; }
  k_convert_smalls<<<dim3(NS), blk, 0, stream>>>(tab, dflag);

  // front weight transposes (raw src + flag)
  k_transT<false><<<dim3(2, 8, 1), blk, 0, stream>>>(base_w1, 0, 0, Wt1, 0, DIN_, DH_, 128, 512, nullptr, dflag);
  k_transT<false><<<dim3(1, 8, 1), blk, 0, stream>>>(em_w,    0, 0, Wem, 0, DEM_, DH_, 64, 512, nullptr, dflag);
  k_transT<false><<<dim3(7, 8, 1), blk, 0, stream>>>(base_w2, 0, 0, Wt2, 0, DH_, DH_, DHP_, 512, nullptr, dflag);
  k_transT<false><<<dim3(7, 4, 1), blk, 0, stream>>>(gfc_w1,  0, 0, Wg1, 0, DH_, GH_, DHP_, GH_, nullptr, dflag);
  k_transT<false><<<dim3(4, 4, 1), blk, 0, stream>>>(gfc_w2,  0, 0, Wg2, 0, GH_, GH_, GH_, GH_, nullptr, dflag);
  // gate weight transposes (converted bf16 src)
  k_transT<false><<<dim3(4, 1, 1), blk, 0, stream>>>(gw0w, 0, 0, gw0t, 0, 256, 16, 256, 16, nullptr, nullptr);
  k_transT<false><<<dim3(4, 1, 1), blk, 0, stream>>>(gw1w, 0, 0, gw1t, 0, 256, 16, 256, 16, nullptr, nullptr);
  k_transT<false><<<dim3(4, 1, 1), blk, 0, stream>>>(gw2w, 0, 0, gw2t, 0, 256, 16, 256, 16, nullptr, nullptr);
  k_transT<false><<<dim3(4, 1, 1), blk, 0, stream>>>(gwLw, 0, 0, gwLt, 0, 256, 4, 256, 4, nullptr, nullptr);

  // front MLPs
  k_gemm_bias<4,  true , false><<<dim3(128, 4), blk, 0, stream>>>(xc, DIN_, Wt1, 128, b1c, DH_, out1, DHP_, DHP_, layC);
  k_gemm_bias<2,  false, false><<<dim3(128, 4), blk, 0, stream>>>(embc, DEM_, Wem, 64, embbc, DH_, emb0, DHP_, DHP_, layC);
  k_gemm_base2<<<dim3(128, 4), blk, 0, stream>>>(out1, Wt2, b2c, emb0, outA, emb1, psO, pqO, layC);
  k_stats<true><<<dim3(1, NCH), blk, 0, stream>>>(outA, 1, psO, pqO, layC);   // fallback (lay!=0)
  bf16_t* emb2 = emb0;  // emb0 dead after base2 -> reuse
  k_gemm_bias<13, true , false><<<dim3(128, 2), blk, 0, stream>>>(emb1, DHP_, Wg1, DHP_, g1bc, GH_, emb2, GH_, GH_, layC);
  k_gemm_bias<8,  false, true ><<<dim3(128, 2), blk, 0, stream>>>(emb2, GH_, Wg2, GH_, g2bc, GH_, embF, GH_, GH_, layC);

  // gating cascade
  k_gate<<<dim3(BN_ / 4), blk, 0, stream>>>(embF,
      gw0t, gw0b, c1w, c1b, gw1t, gw1b, c2w, c2b, gw2t, gw2b,
      cLw, cLb, gwLt, gwLb, wbuf);

  // layer 0
  k_bnprep<<<dim3(7), blk, 0, stream>>>(psO, pqO, 0, bn1g, bn1b, s1, t1);
  k_transT<true><<<dim3(7, 8, 4), blk, 0, stream>>>(modW_raw, 0, (size_t)DH_ * DH_,
                                                    WtM, (size_t)DHA_ * DHP_, DH_, DH_, DHP_, DHA_, s1, dflag);
  k_foldB<<<dim3(4, 7), blk, 0, stream>>>(modW_raw, 0, modbc, t1, bM, dflag);
  k_gemm_mod<<<dim3(128, 4, 4), blk, 0, stream>>>(outA, DHP_, 0, WtM, bM, mo, psB, pqB, layC);
  k_stats<true><<<dim3(4, NCH), blk, 0, stream>>>(mo, MM_, psB, pqB, layC);   // fallback

  // layers 1..3
  for (int L = 1; L < 4; ++L) {
    k_bnprep<<<dim3(7), blk, 0, stream>>>(psB, pqB, 1,
        bn2g + (size_t)(L - 1) * MM_ * DH_, bn2b + (size_t)(L - 1) * MM_ * DH_, s2, t2);
    k_mix<<<dim3(1024), blk, 0, stream>>>(mo, s2, t2, wbuf, (L - 1) * 16, mi);
    k_stats<false><<<dim3(4, NCH), blk, 0, stream>>>(mi, MM_, psA, pqA, layC);
    k_bnprep<<<dim3(7), blk, 0, stream>>>(psA, pqA, 1,
        bn1g + (size_t)L * MM_ * DH_, bn1b + (size_t)L * MM_ * DH_, s1, t1);
    k_transT<true><<<dim3(7, 8, 4), blk, 0, stream>>>(modW_raw, (size_t)L * MM_ * DH_ * DH_, (size_t)DH_ * DH_,
                                                      WtM, (size_t)DHA_ * DHP_, DH_, DH_, DHP_, DHA_, s1, dflag);
    k_foldB<<<dim3(4, 7), blk, 0, stream>>>(modW_raw, (size_t)L * MM_ * DH_ * DH_, modbc + (size_t)L * MM_ * DH_, t1, bM, dflag);
    k_gemm_mod<<<dim3(128, 4, 4), blk, 0, stream>>>(mi, MM_ * DHP_, DHP_, WtM, bM, mo, psB, pqB, layC);
    k_stats<true><<<dim3(4, NCH), blk, 0, stream>>>(mo, MM_, psB, pqB, layC); // fallback
  }

  // final
  k_bnprep<<<dim3(7), blk, 0, stream>>>(psB, pqB, 1,
      bn2g + (size_t)3 * MM_ * DH_, bn2b + (size_t)3 * MM_ * DH_, s2, t2);
  k_final<<<dim3(1024), blk, 0, stream>>>(mo, s2, t2, wbuf, lastw, lastb, d_out, dflag);
}

// Round 6
// 959.114 us; speedup vs baseline: 2.3473x; 1.0671x over previous
//
#include <hip/hip_runtime.h>
#include <hip/hip_bf16.h>

typedef __bf16 bf16_t;
typedef __bf16 bf16x8 __attribute__((ext_vector_type(8)));
typedef __bf16 bf16x4 __attribute__((ext_vector_type(4)));
typedef float  f32x4  __attribute__((ext_vector_type(4)));

#define BN_   16384
#define DIN_  128
#define DEM_  64
#define DH_   400
#define DHP_  416   // K padded to 32-multiple
#define DHA_  512   // N padded to 128-tile coverage
#define GH_   256
#define MM_   4
#define EPS_  1e-5f
#define PCOLS 448   // partial-stats column stride
#define NCH   128   // partial-stats chunks

// ---------------- dtype detector: low-16 of f32 words decodes to garbage bf16
__global__ __launch_bounds__(256) void k_detect(const unsigned* __restrict__ w,
                                                int* __restrict__ flag)
{
  __shared__ int cnt[256];
  int c = 0;
  for (int i = 0; i < 16; ++i) {
    unsigned v = w[threadIdx.x * 16 + i];
    float lo = __uint_as_float((v & 0xffffu) << 16);
    if (!(fabsf(lo) < 1e4f)) ++c;
  }
  cnt[threadIdx.x] = c;
  __syncthreads();
  if (threadIdx.x == 0) {
    int t = 0;
    for (int i = 0; i < 256; ++i) t += cnt[i];
    flag[0] = (t > 64) ? 1 : 0;     // 1 = inputs are float32
  }
}

// ---------------- MFMA C/D layout probe
__global__ void k_mfmaprobe(int* __restrict__ layC)
{
  int l = threadIdx.x & 63;
  bf16x8 av, bv;
#pragma unroll
  for (int e = 0; e < 8; ++e) { av[e] = (bf16_t)0.f; bv[e] = (bf16_t)0.f; }
  if ((l >> 4) == 0) av[0] = (bf16_t)(float)(l & 15);
  if (l == 0)        bv[0] = (bf16_t)1.f;
  f32x4 acc = {0.f, 0.f, 0.f, 0.f};
  acc = __builtin_amdgcn_mfma_f32_16x16x32_bf16(av, bv, acc, 0, 0, 0);
  if (l == 1) layC[0] = (acc[0] > 0.5f) ? 1 : 0;
}

// ---------------- dtype-agnostic converters ---------------------------------
__global__ __launch_bounds__(256) void k_convert(
    const void* __restrict__ src, bf16_t* __restrict__ dst, int n,
    const int* __restrict__ flag)
{
  const int f = flag[0];
  for (int i = blockIdx.x * 256 + threadIdx.x; i < n; i += gridDim.x * 256)
    dst[i] = f ? (bf16_t)((const float*)src)[i] : ((const bf16_t*)src)[i];
}

struct SmallTab {
  const void* src[26];
  bf16_t*     dst[26];
  int         n[26];
};

__global__ __launch_bounds__(256) void k_convert_smalls(SmallTab tab, const int* __restrict__ flag)
{
  const int f = flag[0];
  const void* s = tab.src[blockIdx.x];
  bf16_t*     d = tab.dst[blockIdx.x];
  const int   n = tab.n[blockIdx.x];
  for (int i = threadIdx.x; i < n; i += 256)
    d[i] = f ? (bf16_t)((const float*)s)[i] : ((const bf16_t*)s)[i];
}

// ---------------- tiled transpose (+optional per-k scale fold), coalesced ----
template<bool SCALED>
__global__ __launch_bounds__(256) void k_transT(
    const void* __restrict__ src, size_t srcOff, size_t srcStride,
    bf16_t* __restrict__ dst, size_t dstStride,
    int K, int N, int KP, int NPa,
    const float* __restrict__ scale, const int* __restrict__ flag)
{
  __shared__ float T[64][65];
  const int f = flag ? flag[0] : 0;
  const int z = blockIdx.z;
  const float*  sf = (const float*) src + srcOff + (size_t)z * srcStride;
  const bf16_t* sb = (const bf16_t*)src + srcOff + (size_t)z * srcStride;
  bf16_t* dp = dst + (size_t)z * dstStride;
  const int k0 = blockIdx.x * 64, n0 = blockIdx.y * 64;
  const int lr = threadIdx.x >> 6, ln = threadIdx.x & 63;
#pragma unroll
  for (int p = 0; p < 16; ++p) {
    int kl = p * 4 + lr;
    int k = k0 + kl, n = n0 + ln;
    float v = 0.f;
    if (k < K && n < N)
      v = f ? sf[(size_t)k * N + n] : (float)sb[(size_t)k * N + n];
    if (SCALED && k < K) v *= scale[z * DHP_ + k];
    T[kl][ln] = v;
  }
  __syncthreads();
#pragma unroll
  for (int p = 0; p < 16; ++p) {
    int nl = p * 4 + lr;
    int n = n0 + nl, k = k0 + ln;
    if (n < NPa && k < KP) dp[(size_t)n * KP + k] = (bf16_t)T[ln][nl];
  }
}

// ------------------------- staged GEMM core (m97 structure) ------------------
__device__ __forceinline__ void gload_lds16(const bf16_t* g, bf16_t* l) {
#if __has_builtin(__builtin_amdgcn_global_load_lds)
  __builtin_amdgcn_global_load_lds((const __attribute__((address_space(1))) void*)g,
                                   (__attribute__((address_space(3))) void*)l, 16, 0, 0);
#else
  *(bf16x8*)l = *(const bf16x8*)g;
#endif
}

// stage a 128x32 bf16 tile (8 KB): 512 chunks of 16B; thread t does chunks t, t+256
__device__ __forceinline__ void stage128x32(const bf16_t* __restrict__ g, int ld,
                                            bf16_t* lds, int t) {
  const int c1 = t + 256;
  gload_lds16(g + (size_t)(t  >> 2) * ld + (t  & 3) * 8, lds + t  * 8);
  gload_lds16(g + (size_t)(c1 >> 2) * ld + (c1 & 3) * 8, lds + c1 * 8);
}

__device__ __forceinline__ void acc_zero(f32x4 (&acc)[4][4]) {
  const f32x4 z = {0.f, 0.f, 0.f, 0.f};
#pragma unroll
  for (int i = 0; i < 4; ++i)
#pragma unroll
    for (int j = 0; j < 4; ++j) acc[i][j] = z;
}

// ga/gb pre-offset to (rowTile, 0) / (colTile, 0). KS K-steps of 32.
template<int KS>
__device__ __forceinline__ void gemm_staged(
    const bf16_t* __restrict__ ga, int lda,
    const bf16_t* __restrict__ gb, int ldb,
    bf16_t* ldsA, bf16_t* ldsB,
    int wr, int wc, int rr, int qq, int t,
    f32x4 (&acc)[4][4])
{
  stage128x32(ga, lda, ldsA, t);
  stage128x32(gb, ldb, ldsB, t);
  int cur = 0;
#pragma unroll 1
  for (int ks = 0; ks < KS; ++ks) {
    __syncthreads();                       // staged cur ready (vmcnt drained)
    if (ks + 1 < KS) {
      stage128x32(ga + (ks + 1) * 32, lda, ldsA + (cur ^ 1) * 4096, t);
      stage128x32(gb + (ks + 1) * 32, ldb, ldsB + (cur ^ 1) * 4096, t);
    }
    const bf16_t* la = ldsA + cur * 4096;
    const bf16_t* lb = ldsB + cur * 4096;
    bf16x8 av[4], bv[4];
#pragma unroll
    for (int i = 0; i < 4; ++i)
      av[i] = *reinterpret_cast<const bf16x8*>(la + (wr + i * 16 + rr) * 32 + qq * 8);
#pragma unroll
    for (int i = 0; i < 4; ++i)
      bv[i] = *reinterpret_cast<const bf16x8*>(lb + (wc + i * 16 + rr) * 32 + qq * 8);
#pragma unroll
    for (int i = 0; i < 4; ++i)
#pragma unroll
      for (int j = 0; j < 4; ++j)
        acc[i][j] = __builtin_amdgcn_mfma_f32_16x16x32_bf16(av[i], bv[j], acc[i][j], 0, 0, 0);
    __syncthreads();                       // all waves done reading cur
    cur ^= 1;
  }
}

// ------------------------------------------------- generic bias(+relu) GEMM
template<int KS, bool RELU, bool OUTF32>
__global__ __launch_bounds__(256) void k_gemm_bias(
    const bf16_t* __restrict__ A, int lda,
    const bf16_t* __restrict__ Bt, int ldb,
    const bf16_t* __restrict__ bias, int nbias,
    void* __restrict__ outv, int ldo, int nout,
    const int* __restrict__ layC)
{
  __shared__ bf16_t sA[2 * 4096], sB[2 * 4096];
  const int lay = layC[0];
  const int t = threadIdx.x;
  const int w = t >> 6, lane = t & 63;
  const int rr = lane & 15, qq = lane >> 4;
  const int wr = (w >> 1) * 64, wc = (w & 1) * 64;
  const int rowT = blockIdx.x * 128, colT = blockIdx.y * 128;
  f32x4 acc[4][4]; acc_zero(acc);
  gemm_staged<KS>(A + (size_t)rowT * lda, lda, Bt + (size_t)colT * ldb, ldb,
                  sA, sB, wr, wc, rr, qq, t, acc);
  const int row0 = rowT + wr, col0 = colT + wc;
#pragma unroll
  for (int j = 0; j < 4; ++j) {
#pragma unroll
    for (int i = 0; i < 4; ++i) {
#pragma unroll
      for (int e = 0; e < 4; ++e) {
        int ri = lay ? rr : qq * 4 + e;
        int ci = lay ? qq * 4 + e : rr;
        int row = row0 + i * 16 + ri;
        int col = col0 + j * 16 + ci;
        if (col >= nout) continue;
        float bv = (col < nbias) ? (float)bias[col] : 0.f;
        float v = acc[i][j][e] + bv;
        if (RELU) v = fmaxf(v, 0.f);
        if (OUTF32) ((float*)outv)[(size_t)row * ldo + col] = v;
        else ((bf16_t*)outv)[(size_t)row * ldo + col] = (bf16_t)v;
      }
    }
  }
}

// ---- base layer 2: outA=relu(A@W2+b2); emb1=relu(emb0*(A@W2+b2)); fused stats
__global__ __launch_bounds__(256) void k_gemm_base2(
    const bf16_t* __restrict__ A, const bf16_t* __restrict__ Bt,
    const bf16_t* __restrict__ bias, const bf16_t* __restrict__ emb0,
    bf16_t* __restrict__ outA, bf16_t* __restrict__ emb1,
    float* __restrict__ ps, float* __restrict__ pq,
    const int* __restrict__ layC)
{
  __shared__ bf16_t sA[2 * 4096], sB[2 * 4096];
  __shared__ float rs[2][128], rq[2][128];
  const int lay = layC[0];
  const int t = threadIdx.x;
  const int w = t >> 6, lane = t & 63;
  const int rr = lane & 15, qq = lane >> 4;
  const int wr = (w >> 1) * 64, wc = (w & 1) * 64;
  const int rowT = blockIdx.x * 128, colT = blockIdx.y * 128;
  f32x4 acc[4][4]; acc_zero(acc);
  gemm_staged<13>(A + (size_t)rowT * DHP_, DHP_, Bt + (size_t)colT * DHP_, DHP_,
                  sA, sB, wr, wc, rr, qq, t, acc);
  const int row0 = rowT + wr, col0 = colT + wc;
  float s[4] = {0.f, 0.f, 0.f, 0.f}, q[4] = {0.f, 0.f, 0.f, 0.f};
#pragma unroll
  for (int j = 0; j < 4; ++j) {
#pragma unroll
    for (int i = 0; i < 4; ++i) {
#pragma unroll
      for (int e = 0; e < 4; ++e) {
        int ri = lay ? rr : qq * 4 + e;
        int ci = lay ? qq * 4 + e : rr;
        int row = row0 + i * 16 + ri;
        int col = col0 + j * 16 + ci;
        if (col >= DHP_) continue;
        float bv = (col < DH_) ? (float)bias[col] : 0.f;
        float op = acc[i][j][e] + bv;
        float o  = fmaxf(op, 0.f);
        float e0 = (float)emb0[(size_t)row * DHP_ + col];
        float m1 = fmaxf(e0 * op, 0.f);
        outA[(size_t)row * DHP_ + col] = (bf16_t)o;
        emb1[(size_t)row * DHP_ + col] = (bf16_t)m1;
        s[j] += o; q[j] += o * o;
      }
    }
  }
#pragma unroll
  for (int j = 0; j < 4; ++j) {
    s[j] += __shfl_xor(s[j], 16); s[j] += __shfl_xor(s[j], 32);
    q[j] += __shfl_xor(q[j], 16); q[j] += __shfl_xor(q[j], 32);
  }
  if (lane < 16) {
#pragma unroll
    for (int j = 0; j < 4; ++j) {
      rs[w >> 1][(w & 1) * 64 + j * 16 + lane] = s[j];
      rq[w >> 1][(w & 1) * 64 + j * 16 + lane] = q[j];
    }
  }
  __syncthreads();
  if (lay == 0 && t < 128) {
    int col = blockIdx.y * 128 + t;
    if (col < PCOLS) {
      ps[((size_t)blockIdx.x * MM_ + 0) * PCOLS + col] = rs[0][t] + rs[1][t];
      pq[((size_t)blockIdx.x * MM_ + 0) * PCOLS + col] = rq[0][t] + rq[1][t];
    }
  }
}

// ---- module GEMM: mo[b][m][:] = A_m[b][:] @ W'_m + b'_m; fused mo stats
__global__ __launch_bounds__(256) void k_gemm_mod(
    const bf16_t* __restrict__ Abase, int lda, int mstride,
    const bf16_t* __restrict__ WtM, const float* __restrict__ bM,
    bf16_t* __restrict__ mo,
    float* __restrict__ ps, float* __restrict__ pq,
    const int* __restrict__ layC)
{
  __shared__ bf16_t sA[2 * 4096], sB[2 * 4096];
  __shared__ float rs[2][128], rq[2][128];
  const int lay = layC[0];
  const int m = blockIdx.z;
  const int t = threadIdx.x;
  const int w = t >> 6, lane = t & 63;
  const int rr = lane & 15, qq = lane >> 4;
  const int wr = (w >> 1) * 64, wc = (w & 1) * 64;
  const int rowT = blockIdx.x * 128, colT = blockIdx.y * 128;
  f32x4 acc[4][4]; acc_zero(acc);
  gemm_staged<13>(Abase + (size_t)m * mstride + (size_t)rowT * lda, lda,
                  WtM + (size_t)m * DHA_ * DHP_ + (size_t)colT * DHP_, DHP_,
                  sA, sB, wr, wc, rr, qq, t, acc);
  const int row0 = rowT + wr, col0 = colT + wc;
  float s[4] = {0.f, 0.f, 0.f, 0.f}, q[4] = {0.f, 0.f, 0.f, 0.f};
#pragma unroll
  for (int j = 0; j < 4; ++j) {
#pragma unroll
    for (int i = 0; i < 4; ++i) {
#pragma unroll
      for (int e = 0; e < 4; ++e) {
        int ri = lay ? rr : qq * 4 + e;
        int ci = lay ? qq * 4 + e : rr;
        int row = row0 + i * 16 + ri;
        int col = col0 + j * 16 + ci;
        if (col >= DHP_) continue;
        float v = acc[i][j][e] + bM[m * DHA_ + col];
        mo[((size_t)row * MM_ + m) * DHP_ + col] = (bf16_t)v;
        s[j] += v; q[j] += v * v;
      }
    }
  }
#pragma unroll
  for (int j = 0; j < 4; ++j) {
    s[j] += __shfl_xor(s[j], 16); s[j] += __shfl_xor(s[j], 32);
    q[j] += __shfl_xor(q[j], 16); q[j] += __shfl_xor(q[j], 32);
  }
  if (lane < 16) {
#pragma unroll
    for (int j = 0; j < 4; ++j) {
      rs[w >> 1][(w & 1) * 64 + j * 16 + lane] = s[j];
      rq[w >> 1][(w & 1) * 64 + j * 16 + lane] = q[j];
    }
  }
  __syncthreads();
  if (lay == 0 && t < 128) {
    int col = blockIdx.y * 128 + t;
    if (col < PCOLS) {
      ps[((size_t)blockIdx.x * MM_ + m) * PCOLS + col] = rs[0][t] + rs[1][t];
      pq[((size_t)blockIdx.x * MM_ + m) * PCOLS + col] = rq[0][t] + rq[1][t];
    }
  }
}

// ---------------- stand-alone stats (128-chunk partial layout) ---------------
template<bool GUARDED>
__global__ __launch_bounds__(256) void k_stats(
    const bf16_t* __restrict__ src, int nm,
    float* __restrict__ ps, float* __restrict__ pq,
    const int* __restrict__ layC)
{
  if (GUARDED && layC[0] == 0) return;
  __shared__ float lsum[4 * 52 * 8], lsq[4 * 52 * 8];
  const int m = blockIdx.x, ch = blockIdx.y;
  const int sub = threadIdx.x >> 6, lane = threadIdx.x & 63;
  float s[8], q[8];
#pragma unroll
  for (int e = 0; e < 8; ++e) { s[e] = 0.f; q[e] = 0.f; }
  if (lane < 52) {
    for (int i = 0; i < 32; ++i) {
      int b = ch * 128 + sub + i * 4;
      bf16x8 v = *reinterpret_cast<const bf16x8*>(src + ((size_t)b * nm + m) * DHP_ + lane * 8);
#pragma unroll
      for (int e = 0; e < 8; ++e) {
        float f = (float)v[e];
        s[e] += f; q[e] += f * f;
      }
    }
#pragma unroll
    for (int e = 0; e < 8; ++e) {
      lsum[(sub * 52 + lane) * 8 + e] = s[e];
      lsq [(sub * 52 + lane) * 8 + e] = q[e];
    }
  }
  __syncthreads();
  for (int idx = threadIdx.x; idx < 416; idx += 256) {
    float S = lsum[idx] + lsum[416 + idx] + lsum[832 + idx] + lsum[1248 + idx];
    float Q = lsq [idx] + lsq [416 + idx] + lsq [832 + idx] + lsq [1248 + idx];
    ps[((size_t)ch * MM_ + m) * PCOLS + idx] = S;
    pq[((size_t)ch * MM_ + m) * PCOLS + idx] = Q;
  }
}

// ---------------- partials -> BN scale/shift per (m,d) -----------------------
__global__ __launch_bounds__(256) void k_bnprep(
    const float* __restrict__ ps, const float* __restrict__ pq, int per_m,
    const bf16_t* __restrict__ g, const bf16_t* __restrict__ b,
    float* __restrict__ s_o, float* __restrict__ t_o)
{
  int idx = blockIdx.x * 256 + threadIdx.x;
  if (idx >= MM_ * DHP_) return;
  int m = idx / DHP_, k = idx - m * DHP_;
  float s = 0.f, t = 0.f;
  if (k < DH_) {
    int mm = per_m ? m : 0;
    float S = 0.f, Q = 0.f;
    for (int ch = 0; ch < NCH; ++ch) {
      S += ps[((size_t)ch * MM_ + mm) * PCOLS + k];
      Q += pq[((size_t)ch * MM_ + mm) * PCOLS + k];
    }
    float mean = S * (1.f / BN_);
    float var  = fmaxf(Q * (1.f / BN_) - mean * mean, 0.f);
    float rstd = rsqrtf(var + EPS_);
    s = (float)g[m * DH_ + k] * rstd;
    t = (float)b[m * DH_ + k] - mean * s;
  }
  s_o[m * DHP_ + k] = s;
  t_o[m * DHP_ + k] = t;
}

// b'_m[n] = mod_b[m][n] + sum_k shift[m][k]*W[m][k][n]  (reads raw modW)
__global__ __launch_bounds__(256) void k_foldB(
    const void* __restrict__ modW, size_t off, const bf16_t* __restrict__ modb,
    const float* __restrict__ t1v, float* __restrict__ bM,
    const int* __restrict__ flag)
{
  __shared__ float ls[256];
  const int f = flag[0];
  const int m = blockIdx.x, ncg = blockIdx.y;
  const int t = threadIdx.x;
  const int n = ncg * 64 + (t & 63);
  const int ks = t >> 6;
  float a = 0.f;
  if (n < DH_) {
    for (int k = ks * 100; k < ks * 100 + 100; ++k) {
      size_t idx = off + ((size_t)m * DH_ + k) * DH_ + n;
      float wv = f ? ((const float*)modW)[idx] : (float)((const bf16_t*)modW)[idx];
      a += t1v[m * DHP_ + k] * wv;
    }
  }
  ls[t] = a;
  __syncthreads();
  if (t < 64) {
    int nn = ncg * 64 + t;
    float v = ls[t] + ls[t + 64] + ls[t + 128] + ls[t + 192];
    if (nn < DH_) v += (float)modb[m * DH_ + nn];
    else v = 0.f;
    bM[m * DHA_ + nn] = v;
  }
  if (ncg == 6 && t < 64) bM[m * DHA_ + 448 + t] = 0.f;
}

// ---------------- routing mix (wave-per-sample, coalesced) -------------------
__global__ __launch_bounds__(256) void k_mix(
    const bf16_t* __restrict__ mo, const float* __restrict__ s2v, const float* __restrict__ t2v,
    const float* __restrict__ wbuf, int woff, bf16_t* __restrict__ mi)
{
  const int wave = threadIdx.x >> 6, lane = threadIdx.x & 63;
  const int d0 = lane * 8;
  float sx[4][8], tx[4][8];
  if (lane < 52) {
#pragma unroll
    for (int k = 0; k < 4; ++k)
#pragma unroll
      for (int e = 0; e < 8; ++e) {
        sx[k][e] = s2v[k * DHP_ + d0 + e];
        tx[k][e] = t2v[k * DHP_ + d0 + e];
      }
  }
  for (int b = blockIdx.x * 4 + wave; b < BN_; b += gridDim.x * 4) {
    float wv = (lane < 16) ? wbuf[(size_t)b * 52 + woff + lane] : 0.f;
    if (lane < 52) {
      float x[4][8];
#pragma unroll
      for (int k = 0; k < 4; ++k) {
        bf16x8 v = *reinterpret_cast<const bf16x8*>(mo + ((size_t)b * MM_ + k) * DHP_ + d0);
#pragma unroll
        for (int e = 0; e < 8; ++e)
          x[k][e] = (float)v[e] * sx[k][e] + tx[k][e];
      }
#pragma unroll
      for (int j = 0; j < 4; ++j) {
        float w0 = __shfl(wv, j * 4 + 0), w1 = __shfl(wv, j * 4 + 1);
        float w2 = __shfl(wv, j * 4 + 2), w3 = __shfl(wv, j * 4 + 3);
        bf16x8 ov;
#pragma unroll
        for (int e = 0; e < 8; ++e) {
          float a = x[0][e] * w0 + x[1][e] * w1 + x[2][e] * w2 + x[3][e] * w3;
          ov[e] = (bf16_t)fmaxf(a, 0.f);
        }
        *reinterpret_cast<bf16x8*>(mi + ((size_t)b * MM_ + j) * DHP_ + d0) = ov;
      }
    }
  }
}

// --------------------------- gating cascade: 1 wave = 1 block = 1 sample -----
__global__ __launch_bounds__(64) void k_gate(
    const float* __restrict__ emb,
    const bf16_t* __restrict__ gw0t, const bf16_t* __restrict__ gw0_b,
    const bf16_t* __restrict__ c1_w,  const bf16_t* __restrict__ c1_b,
    const bf16_t* __restrict__ gw1t, const bf16_t* __restrict__ gw1_b,
    const bf16_t* __restrict__ c2_w,  const bf16_t* __restrict__ c2_b,
    const bf16_t* __restrict__ gw2t, const bf16_t* __restrict__ gw2_b,
    const bf16_t* __restrict__ cL_w,  const bf16_t* __restrict__ cL_b,
    const bf16_t* __restrict__ gwLt, const bf16_t* __restrict__ gwL_b,
    float* __restrict__ wbuf)
{
  __shared__ float vb[272];    // +4 pad per 64-float chunk
  __shared__ float fl[64];
  const int lane = threadIdx.x;
  const int b = blockIdx.x;
  const int wrIdx = lane * 4 + (lane >> 4) * 4;

  float e4[4];
  {
    f32x4 ev = *reinterpret_cast<const f32x4*>(emb + (size_t)b * GH_ + lane * 4);
    f32x4 rv;
#pragma unroll
    for (int e = 0; e < 4; ++e) { e4[e] = ev[e]; rv[e] = fmaxf(ev[e], 0.f); }
    *reinterpret_cast<f32x4*>(vb + wrIdx) = rv;
  }
  __syncthreads();

  const int hh = lane >> 4, jj = lane & 15;

  auto gw_phase = [&](const bf16_t* Wt, const bf16_t* Bb, int foff) {
    float a = 0.f;
#pragma unroll
    for (int cc = 0; cc < 8; ++cc) {
      int c8 = (cc + hh * 2) & 7;
      int k  = hh * 64 + c8 * 8;
      int idx = k + hh * 4;
      f32x4 v0 = *reinterpret_cast<const f32x4*>(vb + idx);
      f32x4 v1 = *reinterpret_cast<const f32x4*>(vb + idx + 4);
      bf16x8 wv = *reinterpret_cast<const bf16x8*>(Wt + jj * 256 + k);
      a = fmaf(v0[0], (float)wv[0], a);
      a = fmaf(v0[1], (float)wv[1], a);
      a = fmaf(v0[2], (float)wv[2], a);
      a = fmaf(v0[3], (float)wv[3], a);
      a = fmaf(v1[0], (float)wv[4], a);
      a = fmaf(v1[1], (float)wv[5], a);
      a = fmaf(v1[2], (float)wv[6], a);
      a = fmaf(v1[3], (float)wv[7], a);
    }
    a += __shfl_xor(a, 16);
    a += __shfl_xor(a, 32);
    a += (float)Bb[jj];
    float m1 = fmaxf(a, __shfl_xor(a, 1));
    float mx = fmaxf(m1, __shfl_xor(m1, 2));
    float ex = __expf(a - mx);
    float sx = ex + __shfl_xor(ex, 1);
    float sm = sx + __shfl_xor(sx, 2);
    float wv = ex / sm;
    if (lane < 16) { fl[foff + jj] = wv; wbuf[(size_t)b * 52 + foff + jj] = wv; }
    __syncthreads();
  };

  auto cond_phase = [&](const bf16_t* W, const bf16_t* Bb, int tcount) {
    float a4[4];
    bf16x4 bb = *reinterpret_cast<const bf16x4*>(Bb + lane * 4);
#pragma unroll
    for (int e = 0; e < 4; ++e) a4[e] = (float)bb[e];
    for (int t = 0; t < tcount; ++t) {
      float f = fl[t];
      bf16x4 wv = *reinterpret_cast<const bf16x4*>(W + t * 256 + lane * 4);
#pragma unroll
      for (int e = 0; e < 4; ++e) a4[e] = fmaf(f, (float)wv[e], a4[e]);
    }
    f32x4 rv;
#pragma unroll
    for (int e = 0; e < 4; ++e) rv[e] = fmaxf(a4[e] * e4[e], 0.f);
    *reinterpret_cast<f32x4*>(vb + wrIdx) = rv;
    __syncthreads();
  };

  gw_phase(gw0t, gw0_b, 0);
  cond_phase(c1_w, c1_b, 16);
  gw_phase(gw1t, gw1_b, 16);
  cond_phase(c2_w, c2_b, 32);
  gw_phase(gw2t, gw2_b, 32);
  cond_phase(cL_w, cL_b, 48);
  {
    const int j4 = lane & 3, h16 = lane >> 2;
    const int base = h16 * 16 + (h16 >> 2) * 4;
    bf16x8 w0 = *reinterpret_cast<const bf16x8*>(gwLt + j4 * 256 + h16 * 16);
    bf16x8 w1 = *reinterpret_cast<const bf16x8*>(gwLt + j4 * 256 + h16 * 16 + 8);
    float a = 0.f;
#pragma unroll
    for (int c = 0; c < 2; ++c) {
      f32x4 v0 = *reinterpret_cast<const f32x4*>(vb + base + c * 8);
      f32x4 v1 = *reinterpret_cast<const f32x4*>(vb + base + c * 8 + 4);
      const bf16x8& w = c ? w1 : w0;
      a = fmaf(v0[0], (float)w[0], a);
      a = fmaf(v0[1], (float)w[1], a);
      a = fmaf(v0[2], (float)w[2], a);
      a = fmaf(v0[3], (float)w[3], a);
      a = fmaf(v1[0], (float)w[4], a);
      a = fmaf(v1[1], (float)w[5], a);
      a = fmaf(v1[2], (float)w[6], a);
      a = fmaf(v1[3], (float)w[7], a);
    }
    a += __shfl_xor(a, 4);
    a += __shfl_xor(a, 8);
    a += __shfl_xor(a, 16);
    a += __shfl_xor(a, 32);
    a += (float)gwL_b[j4];
    float m1 = fmaxf(a, __shfl_xor(a, 1));
    float mx = fmaxf(m1, __shfl_xor(m1, 2));
    float ex = __expf(a - mx);
    float sx = ex + __shfl_xor(ex, 1);
    float sm = sx + __shfl_xor(sx, 2);
    if (lane < 4) wbuf[(size_t)b * 52 + 48 + j4] = ex / sm;
  }
}

// ------------- final: BN2-affine, last_weight mix, relu, @last_w + last_b ----
__global__ __launch_bounds__(256) void k_final(
    const bf16_t* __restrict__ mo, const float* __restrict__ s2v, const float* __restrict__ t2v,
    const float* __restrict__ wbuf, const bf16_t* __restrict__ last_w,
    const bf16_t* __restrict__ last_b, void* __restrict__ outv,
    const int* __restrict__ flag)
{
  const int f32out = flag[0];
  const int wave = threadIdx.x >> 6, lane = threadIdx.x & 63;
  const int d0 = lane * 8;
  float sx[4][8], tx[4][8];
  if (lane < 52) {
#pragma unroll
    for (int k = 0; k < 4; ++k)
#pragma unroll
      for (int e = 0; e < 8; ++e) {
        sx[k][e] = s2v[k * DHP_ + d0 + e];
        tx[k][e] = t2v[k * DHP_ + d0 + e];
      }
  }
  for (int b = blockIdx.x * 4 + wave; b < BN_; b += gridDim.x * 4) {
    const float* lwp = wbuf + (size_t)b * 52 + 48;
    float lm0 = lwp[0], lm1 = lwp[1], lm2 = lwp[2], lm3 = lwp[3];
    float slm = lm0 + lm1 + lm2 + lm3;
    const float* w0p = wbuf + (size_t)b * 52;
    float sw0 = w0p[0] + w0p[1] + w0p[2] + w0p[3];
    float p[8];
#pragma unroll
    for (int j = 0; j < 8; ++j) p[j] = 0.f;
    if (lane < 52) {
      float x[4][8];
#pragma unroll
      for (int k = 0; k < 4; ++k) {
        bf16x8 v = *reinterpret_cast<const bf16x8*>(mo + ((size_t)b * MM_ + k) * DHP_ + d0);
#pragma unroll
        for (int e = 0; e < 8; ++e)
          x[k][e] = (float)v[e] * sx[k][e] + tx[k][e];
      }
#pragma unroll
      for (int e = 0; e < 8; ++e) {
        float v = fmaxf(x[0][e] * lm0 + x[1][e] * lm1 + x[2][e] * lm2 + x[3][e] * lm3, 0.f);
        bf16x8 wv = *reinterpret_cast<const bf16x8*>(last_w + (size_t)(d0 + e) * 8);
#pragma unroll
        for (int j = 0; j < 8; ++j) p[j] = fmaf(v, (float)wv[j], p[j]);
      }
    }
#pragma unroll
    for (int j = 0; j < 8; ++j) {
      p[j] += __shfl_xor(p[j], 1);
      p[j] += __shfl_xor(p[j], 2);
      p[j] += __shfl_xor(p[j], 4);
      p[j] += __shfl_xor(p[j], 8);
      p[j] += __shfl_xor(p[j], 16);
      p[j] += __shfl_xor(p[j], 32);
    }
    float sel = p[0];
#pragma unroll
    for (int j = 1; j < 8; ++j) if (lane == j) sel = p[j];
    if (lane < 8) {
      float res = sel + (float)last_b[lane];
      if (!(fabsf(res) < 1e4f)) res = 400.f;
      if (!(slm > 0.97f && slm < 1.03f)) res = 1000.f;
      if (!(sw0 > 0.97f && sw0 < 1.03f)) res = 2000.f;
      if (f32out) ((float*)outv)[(size_t)b * 8 + lane] = res;
      else ((bf16_t*)outv)[(size_t)b * 8 + lane] = (bf16_t)res;
    }
  }
}

// ======================================================================
extern "C" void kernel_launch(void* const* d_in, const int* in_sizes, int n_in,
                              void* d_out, int out_size, void* d_ws, size_t ws_size,
                              hipStream_t stream)
{
  (void)in_sizes; (void)n_in;
  const void* x_raw   = d_in[0];
  const void* emb_raw = d_in[1];
  const void* base_w1 = d_in[2];
  const void* base_w2 = d_in[4];
  const void* em_w    = d_in[6];
  const void* gfc_w1  = d_in[8];
  const void* gfc_w2  = d_in[10];
  const void* modW_raw= d_in[28];

  char* base = (char*)d_ws;
  size_t off = 0;
  auto alloc = [&](size_t bytes) -> char* {
    off = (off + 255) & ~(size_t)255;
    char* r = base + off; off += bytes; return r;
  };
  int*    dflag = (int*)   alloc(16);
  int*    layC  = (int*)   alloc(16);
  bf16_t* Wt1  = (bf16_t*)alloc((size_t)512 * 128 * 2);
  bf16_t* Wem  = (bf16_t*)alloc((size_t)512 * 64 * 2);
  bf16_t* Wt2  = (bf16_t*)alloc((size_t)512 * DHP_ * 2);
  bf16_t* Wg1  = (bf16_t*)alloc((size_t)256 * DHP_ * 2);
  bf16_t* Wg2  = (bf16_t*)alloc((size_t)256 * 256 * 2);
  bf16_t* WtM  = (bf16_t*)alloc((size_t)MM_ * DHA_ * DHP_ * 2);
  float*  bM   = (float*) alloc((size_t)MM_ * DHA_ * 4);
  bf16_t* xc   = (bf16_t*)alloc((size_t)BN_ * DIN_ * 2);
  bf16_t* embc = (bf16_t*)alloc((size_t)BN_ * DEM_ * 2);
  bf16_t* out1 = (bf16_t*)alloc((size_t)BN_ * DHP_ * 2);
  bf16_t* emb0 = (bf16_t*)alloc((size_t)BN_ * DHP_ * 2);
  bf16_t* outA = (bf16_t*)alloc((size_t)BN_ * DHP_ * 2);
  bf16_t* emb1 = (bf16_t*)alloc((size_t)BN_ * DHP_ * 2);
  float*  embF = (float*) alloc((size_t)BN_ * GH_ * 4);
  float*  wbuf = (float*) alloc((size_t)BN_ * 52 * 4);
  bf16_t* mo   = (bf16_t*)alloc((size_t)BN_ * MM_ * DHP_ * 2);
  bf16_t* mi   = (bf16_t*)alloc((size_t)BN_ * MM_ * DHP_ * 2);
  float* psO = (float*)alloc((size_t)NCH * MM_ * PCOLS * 4);
  float* pqO = (float*)alloc((size_t)NCH * MM_ * PCOLS * 4);
  float* psA = (float*)alloc((size_t)NCH * MM_ * PCOLS * 4);
  float* pqA = (float*)alloc((size_t)NCH * MM_ * PCOLS * 4);
  float* psB = (float*)alloc((size_t)NCH * MM_ * PCOLS * 4);
  float* pqB = (float*)alloc((size_t)NCH * MM_ * PCOLS * 4);
  float* s1 = (float*)alloc((size_t)MM_ * DHP_ * 4);
  float* t1 = (float*)alloc((size_t)MM_ * DHP_ * 4);
  float* s2 = (float*)alloc((size_t)MM_ * DHP_ * 4);
  float* t2 = (float*)alloc((size_t)MM_ * DHP_ * 4);
  bf16_t* gw0t = (bf16_t*)alloc((size_t)16 * 256 * 2);
  bf16_t* gw1t = (bf16_t*)alloc((size_t)16 * 256 * 2);
  bf16_t* gw2t = (bf16_t*)alloc((size_t)16 * 256 * 2);
  bf16_t* gwLt = (bf16_t*)alloc((size_t)4 * 256 * 2);
  const int NS = 26;
  const int sn[NS] = {400, 400, 400, 256, 256,
                      4096, 16, 4096, 256, 4096, 16, 8192, 256, 4096, 16,
                      12288, 256, 1024, 4,
                      6400, 6400, 6400, 6400, 6400, 3200, 8};
  const int si[NS] = {3, 5, 7, 9, 11,
                      12, 13, 14, 15, 16, 17, 18, 19, 20, 21,
                      22, 23, 24, 25,
                      26, 27, 29, 30, 31, 32, 33};
  bf16_t* sc[NS];
  for (int i = 0; i < NS; ++i) sc[i] = (bf16_t*)alloc((size_t)sn[i] * 2);
  bf16_t *b1c = sc[0], *b2c = sc[1], *embbc = sc[2], *g1bc = sc[3], *g2bc = sc[4];
  bf16_t *gw0w = sc[5], *gw0b = sc[6], *c1w = sc[7], *c1b = sc[8], *gw1w = sc[9],
         *gw1b = sc[10], *c2w = sc[11], *c2b = sc[12], *gw2w = sc[13], *gw2b = sc[14],
         *cLw = sc[15], *cLb = sc[16], *gwLw = sc[17], *gwLb = sc[18];
  bf16_t *bn1g = sc[19], *bn1b = sc[20], *modbc = sc[21], *bn2g = sc[22], *bn2b = sc[23];
  bf16_t *lastw = sc[24], *lastb = sc[25];

  if (off > ws_size) {
    hipMemsetAsync(d_out, 0, (size_t)out_size * 2, stream);
    return;
  }

  dim3 blk(256);
  k_detect<<<1, blk, 0, stream>>>((const unsigned*)x_raw, dflag);
  k_mfmaprobe<<<1, dim3(64), 0, stream>>>(layC);

  k_convert<<<dim3(2048), blk, 0, stream>>>(x_raw,   xc,    BN_ * DIN_, dflag);
  k_convert<<<dim3(1024), blk, 0, stream>>>(emb_raw, embc,  BN_ * DEM_, dflag);
  SmallTab tab;
  for (int i = 0; i < NS; ++i) { tab.src[i] = d_in[si[i]]; tab.dst[i] = sc[i]; tab.n[i] = sn[i]; }
  k_convert_smalls<<<dim3(NS), blk, 0, stream>>>(tab, dflag);

  // front weight transposes (raw src + flag)
  k_transT<false><<<dim3(2, 8, 1), blk, 0, stream>>>(base_w1, 0, 0, Wt1, 0, DIN_, DH_, 128, 512, nullptr, dflag);
  k_transT<false><<<dim3(1, 8, 1), blk, 0, stream>>>(em_w,    0, 0, Wem, 0, DEM_, DH_, 64, 512, nullptr, dflag);
  k_transT<false><<<dim3(7, 8, 1), blk, 0, stream>>>(base_w2, 0, 0, Wt2, 0, DH_, DH_, DHP_, 512, nullptr, dflag);
  k_transT<false><<<dim3(7, 4, 1), blk, 0, stream>>>(gfc_w1,  0, 0, Wg1, 0, DH_, GH_, DHP_, GH_, nullptr, dflag);
  k_transT<false><<<dim3(4, 4, 1), blk, 0, stream>>>(gfc_w2,  0, 0, Wg2, 0, GH_, GH_, GH_, GH_, nullptr, dflag);
  // gate weight transposes (converted bf16 src)
  k_transT<false><<<dim3(4, 1, 1), blk, 0, stream>>>(gw0w, 0, 0, gw0t, 0, 256, 16, 256, 16, nullptr, nullptr);
  k_transT<false><<<dim3(4, 1, 1), blk, 0, stream>>>(gw1w, 0, 0, gw1t, 0, 256, 16, 256, 16, nullptr, nullptr);
  k_transT<false><<<dim3(4, 1, 1), blk, 0, stream>>>(gw2w, 0, 0, gw2t, 0, 256, 16, 256, 16, nullptr, nullptr);
  k_transT<false><<<dim3(4, 1, 1), blk, 0, stream>>>(gwLw, 0, 0, gwLt, 0, 256, 4, 256, 4, nullptr, nullptr);

  // front MLPs (staged GEMMs)
  k_gemm_bias<4,  true , false><<<dim3(128, 4), blk, 0, stream>>>(xc, DIN_, Wt1, 128, b1c, DH_, out1, DHP_, DHP_, layC);
  k_gemm_bias<2,  false, false><<<dim3(128, 4), blk, 0, stream>>>(embc, DEM_, Wem, 64, embbc, DH_, emb0, DHP_, DHP_, layC);
  k_gemm_base2<<<dim3(128, 4), blk, 0, stream>>>(out1, Wt2, b2c, emb0, outA, emb1, psO, pqO, layC);
  k_stats<true><<<dim3(1, NCH), blk, 0, stream>>>(outA, 1, psO, pqO, layC);   // fallback (lay!=0)
  bf16_t* emb2 = emb0;  // emb0 dead after base2 -> reuse
  k_gemm_bias<13, true , false><<<dim3(128, 2), blk, 0, stream>>>(emb1, DHP_, Wg1, DHP_, g1bc, GH_, emb2, GH_, GH_, layC);
  k_gemm_bias<8,  false, true ><<<dim3(128, 2), blk, 0, stream>>>(emb2, GH_, Wg2, GH_, g2bc, GH_, embF, GH_, GH_, layC);

  // gating cascade (1 wave per sample)
  k_gate<<<dim3(BN_), dim3(64), 0, stream>>>(embF,
      gw0t, gw0b, c1w, c1b, gw1t, gw1b, c2w, c2b, gw2t, gw2b,
      cLw, cLb, gwLt, gwLb, wbuf);

  // layer 0
  k_bnprep<<<dim3(7), blk, 0, stream>>>(psO, pqO, 0, bn1g, bn1b, s1, t1);
  k_transT<true><<<dim3(7, 8, 4), blk, 0, stream>>>(modW_raw, 0, (size_t)DH_ * DH_,
                                                    WtM, (size_t)DHA_ * DHP_, DH_, DH_, DHP_, DHA_, s1, dflag);
  k_foldB<<<dim3(4, 7), blk, 0, stream>>>(modW_raw, 0, modbc, t1, bM, dflag);
  k_gemm_mod<<<dim3(128, 4, 4), blk, 0, stream>>>(outA, DHP_, 0, WtM, bM, mo, psB, pqB, layC);
  k_stats<true><<<dim3(4, NCH), blk, 0, stream>>>(mo, MM_, psB, pqB, layC);   // fallback

  // layers 1..3
  for (int L = 1; L < 4; ++L) {
    k_bnprep<<<dim3(7), blk, 0, stream>>>(psB, pqB, 1,
        bn2g + (size_t)(L - 1) * MM_ * DH_, bn2b + (size_t)(L - 1) * MM_ * DH_, s2, t2);
    k_mix<<<dim3(1024), blk, 0, stream>>>(mo, s2, t2, wbuf, (L - 1) * 16, mi);
    k_stats<false><<<dim3(4, NCH), blk, 0, stream>>>(mi, MM_, psA, pqA, layC);
    k_bnprep<<<dim3(7), blk, 0, stream>>>(psA, pqA, 1,
        bn1g + (size_t)L * MM_ * DH_, bn1b + (size_t)L * MM_ * DH_, s1, t1);
    k_transT<true><<<dim3(7, 8, 4), blk, 0, stream>>>(modW_raw, (size_t)L * MM_ * DH_ * DH_, (size_t)DH_ * DH_,
                                                      WtM, (size_t)DHA_ * DHP_, DH_, DH_, DHP_, DHA_, s1, dflag);
    k_foldB<<<dim3(4, 7), blk, 0, stream>>>(modW_raw, (size_t)L * MM_ * DH_ * DH_, modbc + (size_t)L * MM_ * DH_, t1, bM, dflag);
    k_gemm_mod<<<dim3(128, 4, 4), blk, 0, stream>>>(mi, MM_ * DHP_, DHP_, WtM, bM, mo, psB, pqB, layC);
    k_stats<true><<<dim3(4, NCH), blk, 0, stream>>>(mo, MM_, psB, pqB, layC); // fallback
  }

  // final
  k_bnprep<<<dim3(7), blk, 0, stream>>>(psB, pqB, 1,
      bn2g + (size_t)3 * MM_ * DH_, bn2b + (size_t)3 * MM_ * DH_, s2, t2);
  k_final<<<dim3(1024), blk, 0, stream>>>(mo, s2, t2, wbuf, lastw, lastb, d_out, dflag);
}